// Round 6
// baseline (553.922 us; speedup 1.0000x reference)
//
#include <hip/hip_runtime.h>
#include <hip/hip_bf16.h>

using u16 = unsigned short;

typedef __bf16 bf16x8 __attribute__((ext_vector_type(8)));
typedef float  f32x4  __attribute__((ext_vector_type(4)));

typedef __attribute__((address_space(1))) void gas_void;
typedef __attribute__((address_space(3))) void las_void;

__device__ __forceinline__ float b2f(u16 u) {
  union { unsigned u; float f; } v; v.u = ((unsigned)u) << 16; return v.f;
}
__device__ __forceinline__ u16 f2b(float f) {
  union { float f; unsigned u; } v; v.f = f;
  unsigned r = v.u + 0x7fffu + ((v.u >> 16) & 1u);
  return (u16)(r >> 16);
}

// async global->LDS, 16B per lane. LDS dest must be uniform base + lane*16.
__device__ __forceinline__ void gld_lds16(const u16* g, u16* l) {
  __builtin_amdgcn_global_load_lds((gas_void*)g, (las_void*)l, 16, 0, 0);
}

// ---------------------------------------------------------------------------
// Generic NT GEMM: C[m,n] = sum_k A[m,k] * B[n,k], bf16 in, fp32 acc.
// Block tile 128x128, 4 waves (2x2), wave = 4x4 of 16x16x32 MFMA.
// Retained for the small per-(b,h) GEMMs (kv / causal-A / A@V, EPI 1..3).
// ---------------------------------------------------------------------------
template <int EPI, int BK>
__global__ __launch_bounds__(256) void gemm_bt(
    const u16* __restrict__ A, int lda, long sA1, long sA2,
    const u16* __restrict__ B, int ldb, long sB1, long sB2,
    void* __restrict__ Cv, int ldc, long sC1, long sC2,
    int K, int HDIV,
    const float* __restrict__ bias, const float* __restrict__ resid,
    float* __restrict__ partOut) {
  __shared__ __align__(16) u16 lds[2 * 128 * BK];
  __shared__ float denS[128];
  const int t = threadIdx.x;
  const int lane = t & 63;
  const int wave = t >> 6;
  const int wm = wave >> 1, wn = wave & 1;
  const int laneM = lane & 15, quad = lane >> 4;
  const int zb = blockIdx.z / HDIV, zh = blockIdx.z % HDIV;

  int bx = blockIdx.x, by = blockIdx.y;
  if (EPI == 2) { by = (bx >= 1) ? 1 : 0; bx = (bx == 2) ? 1 : 0; }
  const int kEnd = (EPI == 3) ? ((by + 1) * 128 < K ? (by + 1) * 128 : K) : K;

  const u16* Abase = A + zb * sA1 + zh * sA2 + (long)by * 128 * lda;
  const u16* Bbase = B + zb * sB1 + zh * sB2 + (long)bx * 128 * ldb;

  constexpr int STEPS = BK / 16;   // staging steps per operand (2048 elem each)
  constexpr int RPS = 2048 / BK;   // rows per staging step
  constexpr int KK = BK / 32;      // MFMA k-steps per LDS tile
  const int sRow = (BK == 64) ? (t >> 3) : (t >> 2);
  const int sg = (BK == 64) ? (t & 7) : (t & 3);
  const int swz = (BK == 64) ? (sg ^ (sRow & 7)) : (sg ^ ((sRow >> 1) & 3));
  const int sc = swz * 8;  // swizzled global k-chunk offset (elems)

  f32x4 acc[4][4];
#pragma unroll
  for (int i = 0; i < 4; ++i)
#pragma unroll
    for (int j = 0; j < 4; ++j) acc[i][j] = (f32x4){0.f, 0.f, 0.f, 0.f};
  float dsum[4] = {0.f, 0.f, 0.f, 0.f};

  for (int k0 = 0; k0 < kEnd; k0 += BK) {
#pragma unroll
    for (int p = 0; p < STEPS; ++p)
      gld_lds16(Abase + (long)(p * RPS + sRow) * lda + k0 + sc,
                &lds[p * 2048 + t * 8]);
#pragma unroll
    for (int p = 0; p < STEPS; ++p)
      gld_lds16(Bbase + (long)(p * RPS + sRow) * ldb + k0 + sc,
                &lds[128 * BK + p * 2048 + t * 8]);
    __syncthreads();  // drains vmcnt(0): LDS staging complete
    bf16x8 af[KK][4], bfv[KK][4];
#pragma unroll
    for (int kk = 0; kk < KK; ++kk) {
      int perm8;
      if (BK == 64) perm8 = ((kk * 4 + quad) ^ (laneM & 7)) * 8;
      else          perm8 = (quad ^ ((laneM >> 1) & 3)) * 8;
#pragma unroll
      for (int i = 0; i < 4; ++i) {
        af[kk][i] = *(const bf16x8*)&lds[(wm * 64 + i * 16 + laneM) * BK + perm8];
        bfv[kk][i] =
            *(const bf16x8*)&lds[128 * BK + (wn * 64 + i * 16 + laneM) * BK + perm8];
      }
    }
    if (EPI == 3) {  // rowsum of A from fragments (den; mask is pre-applied)
#pragma unroll
      for (int kk = 0; kk < KK; ++kk)
#pragma unroll
        for (int i = 0; i < 4; ++i) {
          union { bf16x8 v; u16 s[8]; } u; u.v = af[kk][i];
          float ds = 0.f;
#pragma unroll
          for (int e = 0; e < 8; ++e) ds += b2f(u.s[e]);
          dsum[i] += ds;
        }
    }
#pragma unroll
    for (int kk = 0; kk < KK; ++kk)
#pragma unroll
      for (int i = 0; i < 4; ++i)
#pragma unroll
        for (int j = 0; j < 4; ++j)
          acc[i][j] = __builtin_amdgcn_mfma_f32_16x16x32_bf16(
              af[kk][i], bfv[kk][j], acc[i][j], 0, 0, 0);
    __syncthreads();  // all waves done reading before next stage
  }

  if (EPI == 3) {
#pragma unroll
    for (int i = 0; i < 4; ++i) {
      float s = dsum[i];
      s += __shfl_xor(s, 16);
      s += __shfl_xor(s, 32);
      if (wn == 0 && quad == 0)
        denS[wm * 64 + i * 16 + laneM] = fmaxf(s, 1e-8f);
    }
    __syncthreads();
  }

  if (EPI == 1) {  // column sums of tile -> part[zh*256 + col] (cs fusion)
#pragma unroll
    for (int j = 0; j < 4; ++j) {
      float s = 0.f;
#pragma unroll
      for (int i = 0; i < 4; ++i)
#pragma unroll
        for (int r = 0; r < 4; ++r) s += acc[i][j][r];
      s += __shfl_xor(s, 16);
      s += __shfl_xor(s, 32);
      if (quad == 0)
        atomicAdd(&partOut[zh * 256 + bx * 128 + wn * 64 + j * 16 + laneM], s);
    }
  }

  const long cOff = zb * sC1 + zh * sC2;
  const int colB = bx * 128 + wn * 64;
#pragma unroll
  for (int i = 0; i < 4; ++i) {
#pragma unroll
    for (int j = 0; j < 4; ++j) {
#pragma unroll
      for (int r = 0; r < 4; ++r) {
        const int lrow = wm * 64 + i * 16 + quad * 4 + r;  // row within block
        const int row = by * 128 + lrow;                   // within-batch row
        const int col = colB + j * 16 + laneM;             // within-batch col
        const long idx = cOff + (long)row * ldc + col;
        float v = acc[i][j][r];
        if (EPI == 0 || EPI == 1) {
          ((u16*)Cv)[idx] = f2b(v);
        } else if (EPI == 2) {
          ((u16*)Cv)[idx] = f2b(col <= row ? v : 0.0f);
        } else if (EPI == 3) {
          ((u16*)Cv)[idx] = f2b(v / denS[lrow]);
        } else {
          ((float*)Cv)[idx] =
              (zb == 0) ? v + bias[col] + resid[(long)row * ldc + col] : v;
        }
      }
    }
  }
}

// ---------------------------------------------------------------------------
// One K-tile (BK=32) of the 256x256 CROSS-HALF-PIPELINED GEMM.
// Frags for tile tau (aIn/bIn) were ds_read during tile tau-1; this tile
// issues reads for tau's second half (aH1) and tile tau+1 (aOut/bOut), and
// waits with COUNTED lgkmcnt so LDS reads stream under the MFMA clusters
// (the R2/R4 2-phase structure waited lgkmcnt(0) on same-phase reads ->
// serialized LDS drain before every MFMA cluster; this removes that).
// One barrier + counted vmcnt per tile (was 4 barriers + per-phase locks).
// Validity ledger: after boundary barrier of tau-1 (vmcnt(4)), buffers for
// tau and tau+1 are DMA-complete; reads during tau touch exactly those.
// Stage during tau targets buf (tau+3)%4, last read two barriers ago (WAR
// safe). sched_barrier(0) after each counted wait (hoist-past-waitcnt bug).
// ---------------------------------------------------------------------------
__device__ __forceinline__ void g256_tile(
    const u16* __restrict__ lc,   // A-buffer of tile tau (half1 frag reads)
    const u16* __restrict__ lnA,  // A-buffer of tile tau+1
    const u16* __restrict__ lnB,  // B-buffer of tile tau+1
    u16* __restrict__ sa, u16* __restrict__ sb,  // stage dests (tile tau+3)
    int tau, int nt,
    const u16* AgR0, const u16* AgR1, const u16* BgR0, const u16* BgR1,
    int rowA, int rowB, int rg, int t,
    bf16x8 (&aIn)[4], bf16x8 (&bIn)[4],    // tile tau frags (older lgkm ops)
    bf16x8 (&aOut)[4], bf16x8 (&bOut)[4],  // tile tau+1 frags (issued here)
    f32x4 (&acc)[8][4]) {
  const bool st = (tau + 3) < nt;
  const int ks = (tau + 3) << 5;
  // ---- half 0: MFMA rows 0..63 with aIn/bIn; read tau half1 A-frags ----
  if (st) {
    gld_lds16(AgR0 + ks, &sa[t * 8]);
    gld_lds16(AgR1 + ks, &sa[4096 + t * 8]);
  }
  bf16x8 aH1[4];
#pragma unroll
  for (int m = 0; m < 4; ++m)
    aH1[m] = *(const bf16x8*)&lc[(rowA + 64 + m * 16) * 32 + rg];
  // 4 newest (aH1) may remain outstanding; the 8 older (aIn/bIn) are done.
  asm volatile("s_waitcnt lgkmcnt(4)" ::: "memory");
  __builtin_amdgcn_sched_barrier(0);
  __builtin_amdgcn_s_setprio(1);
#pragma unroll
  for (int m = 0; m < 4; ++m)
#pragma unroll
    for (int n = 0; n < 4; ++n)
      acc[m][n] = __builtin_amdgcn_mfma_f32_16x16x32_bf16(aIn[m], bIn[n],
                                                          acc[m][n], 0, 0, 0);
  __builtin_amdgcn_s_setprio(0);
  // ---- half 1: MFMA rows 64..127 with aH1/bIn; read tile tau+1 frags ----
  if (st) {
    gld_lds16(BgR0 + ks, &sb[t * 8]);
    gld_lds16(BgR1 + ks, &sb[4096 + t * 8]);
  }
  if (tau + 1 < nt) {
#pragma unroll
    for (int m = 0; m < 4; ++m)
      aOut[m] = *(const bf16x8*)&lnA[(rowA + m * 16) * 32 + rg];
#pragma unroll
    for (int n = 0; n < 4; ++n)
      bOut[n] = *(const bf16x8*)&lnB[(rowB + n * 16) * 32 + rg];
    // 8 newest (aOut/bOut) may remain outstanding; aH1 (older) is done.
    asm volatile("s_waitcnt lgkmcnt(8)" ::: "memory");
  } else {
    asm volatile("s_waitcnt lgkmcnt(0)" ::: "memory");
  }
  __builtin_amdgcn_sched_barrier(0);
  __builtin_amdgcn_s_setprio(1);
#pragma unroll
  for (int m = 0; m < 4; ++m)
#pragma unroll
    for (int n = 0; n < 4; ++n)
      acc[4 + m][n] = __builtin_amdgcn_mfma_f32_16x16x32_bf16(
          aH1[m], bIn[n], acc[4 + m][n], 0, 0, 0);
  __builtin_amdgcn_s_setprio(0);
  // ---- boundary: tau+1's AND tau+2's stages must have landed ----
  if (tau < nt - 1) {
    if (tau + 3 < nt)
      asm volatile("s_waitcnt vmcnt(4)" ::: "memory");
    else
      asm volatile("s_waitcnt vmcnt(0)" ::: "memory");
    __builtin_amdgcn_s_barrier();
  }
}

// ---------------------------------------------------------------------------
// 256x256 NT GEMM, cross-half pipelined, STATIC quad-buffered LDS.
// 512 threads = 8 waves (2 M x 4 N); per-wave 128x64 output = 8x4 16x16 frags.
// 4 separate 16KB buffers per operand (128 KB LDS, 1 block/CU), prefetch
// distance 3 tiles, main loop statically unrolled x4 (nt = 64 or 32, %4==0).
// Frag registers ping-pong between two named sets (static indexing only).
// Grid: flat 8*8*Z, bijective chunked XCD swizzle (grid %8==0).
// EPI 0: bf16 out (proj). EPI 4: fp32 out, z==0 adds bias+resid (Wo splitK).
// ---------------------------------------------------------------------------
template <int EPI>
__global__ __launch_bounds__(512) void gemm256(
    const u16* __restrict__ A, int lda, long sA1,
    const u16* __restrict__ B, int ldb, long sB1,
    void* __restrict__ Cv, int ldc, long sC1, int K,
    const float* __restrict__ bias, const float* __restrict__ resid) {
  __shared__ __align__(16) u16 A0[8192], A1[8192], A2[8192], A3[8192];
  __shared__ __align__(16) u16 B0[8192], B1[8192], B2[8192], B3[8192];
  const int t = threadIdx.x;
  const int lane = t & 63, wave = t >> 6;
  const int wm = wave >> 2, wn = wave & 3;
  const int laneM = lane & 15, quad = lane >> 4;

  const int cpx = gridDim.x >> 3;                      // blocks per XCD chunk
  const int id2 = (blockIdx.x & 7) * cpx + (blockIdx.x >> 3);
  const int bx = id2 & 7, by = (id2 >> 3) & 7, z = id2 >> 6;

  const u16* Ag = A + (long)z * sA1 + (long)by * 256 * lda;
  const u16* Bg = B + (long)z * sB1 + (long)bx * 256 * ldb;

  const int nt = K >> 5;                               // K-tiles of 32
  const int rg = (quad ^ ((laneM >> 1) & 3)) * 8;      // read-granule offset
  const int rowA = wm * 128 + laneM;
  const int rowB = wn * 64 + laneM;

  // staging addresses: thread t covers chunks t and 512+t of each tile
  const int sRow0 = t >> 2, sRow1 = (512 + t) >> 2;
  const int sc0 = (((t) & 3) ^ ((sRow0 >> 1) & 3)) * 8;
  const int sc1 = (((512 + t) & 3) ^ ((sRow1 >> 1) & 3)) * 8;
  const u16* AgR0 = Ag + (long)sRow0 * lda + sc0;
  const u16* AgR1 = Ag + (long)sRow1 * lda + sc1;
  const u16* BgR0 = Bg + (long)sRow0 * ldb + sc0;
  const u16* BgR1 = Bg + (long)sRow1 * ldb + sc1;

  f32x4 acc[8][4];
#pragma unroll
  for (int i = 0; i < 8; ++i)
#pragma unroll
    for (int j = 0; j < 4; ++j) acc[i][j] = (f32x4){0.f, 0.f, 0.f, 0.f};

  // prologue: stage tiles 0,1,2 into bufs 0,1,2.
  gld_lds16(AgR0, &A0[t * 8]);      gld_lds16(AgR1, &A0[4096 + t * 8]);
  gld_lds16(BgR0, &B0[t * 8]);      gld_lds16(BgR1, &B0[4096 + t * 8]);
  gld_lds16(AgR0 + 32, &A1[t * 8]); gld_lds16(AgR1 + 32, &A1[4096 + t * 8]);
  gld_lds16(BgR0 + 32, &B1[t * 8]); gld_lds16(BgR1 + 32, &B1[4096 + t * 8]);
  gld_lds16(AgR0 + 64, &A2[t * 8]); gld_lds16(AgR1 + 64, &A2[4096 + t * 8]);
  gld_lds16(BgR0 + 64, &B2[t * 8]); gld_lds16(BgR1 + 64, &B2[4096 + t * 8]);
  // tiles 0 AND 1 must be landed (tile 0 body reads buf1); tile 2 in flight.
  asm volatile("s_waitcnt vmcnt(4)" ::: "memory");
  __builtin_amdgcn_s_barrier();

  // prologue frag reads: tile 0 half0 A + tile 0 B (8 lgkm ops outstanding)
  bf16x8 aP[4], bP[4], aQ[4], bQ[4];
#pragma unroll
  for (int m = 0; m < 4; ++m)
    aP[m] = *(const bf16x8*)&A0[(rowA + m * 16) * 32 + rg];
#pragma unroll
  for (int n = 0; n < 4; ++n)
    bP[n] = *(const bf16x8*)&B0[(rowB + n * 16) * 32 + rg];

  for (int tau = 0; tau < nt; tau += 4) {
    g256_tile(A0, A1, B1, A3, B3, tau + 0, nt, AgR0, AgR1, BgR0, BgR1,
              rowA, rowB, rg, t, aP, bP, aQ, bQ, acc);
    g256_tile(A1, A2, B2, A0, B0, tau + 1, nt, AgR0, AgR1, BgR0, BgR1,
              rowA, rowB, rg, t, aQ, bQ, aP, bP, acc);
    g256_tile(A2, A3, B3, A1, B1, tau + 2, nt, AgR0, AgR1, BgR0, BgR1,
              rowA, rowB, rg, t, aP, bP, aQ, bQ, acc);
    g256_tile(A3, A0, B0, A2, B2, tau + 3, nt, AgR0, AgR1, BgR0, BgR1,
              rowA, rowB, rg, t, aQ, bQ, aP, bP, acc);
  }

  const long cOff = (long)z * sC1;
  const int colB = bx * 256 + wn * 64;
  const int rowBase = by * 256 + wm * 128;
#pragma unroll
  for (int i = 0; i < 8; ++i) {
#pragma unroll
    for (int j = 0; j < 4; ++j) {
#pragma unroll
      for (int r = 0; r < 4; ++r) {
        const int row = rowBase + i * 16 + quad * 4 + r;
        const int col = colB + j * 16 + laneM;
        const long idx = cOff + (long)row * ldc + col;
        float v = acc[i][j][r];
        if (EPI == 0) {
          ((u16*)Cv)[idx] = f2b(v);
        } else {
          ((float*)Cv)[idx] =
              (z == 0) ? v + bias[col] + resid[(long)row * ldc + col] : v;
        }
      }
    }
  }
}

// ---------------------------------------------------------------------------
// Convert 7 fp32 2048x2048 tensors -> bf16, dsts contiguous from dst base.
// ---------------------------------------------------------------------------
__global__ __launch_bounds__(256) void convert7(
    const float* __restrict__ s0, const float* __restrict__ s1,
    const float* __restrict__ s2, const float* __restrict__ s3,
    const float* __restrict__ s4, const float* __restrict__ s5,
    const float* __restrict__ s6, u16* __restrict__ dst) {
  long idx = (long)blockIdx.x * 256 + threadIdx.x;  // 0 .. 7*1048576-1
  int seg = (int)(idx >> 20);
  long off = (idx & 1048575) << 2;
  const float* s;
  switch (seg) {
    case 0: s = s0; break; case 1: s = s1; break; case 2: s = s2; break;
    case 3: s = s3; break; case 4: s = s4; break; case 5: s = s5; break;
    default: s = s6;
  }
  float4 v = *(const float4*)(s + off);
  ushort4 o;
  o.x = f2b(v.x); o.y = f2b(v.y); o.z = f2b(v.z); o.w = f2b(v.w);
  *(ushort4*)(dst + (long)seg * 4194304 + off) = o;
}

// cs_seq[h,m]: scan over heads collecting the PRE-update carry.
// part[h*256+m] holds sum over (b,l) of kv (from GEMM-epilogue atomics).
__global__ __launch_bounds__(256) void cs_kernel(
    const float* __restrict__ part, float* __restrict__ cs,
    const float* __restrict__ alphaP, const float* __restrict__ betaP) {
  int m = threadIdx.x;
  float alpha = *alphaP, beta = *betaP;
  float c = 0.f;
  for (int h = 0; h < 8; ++h) {
    cs[h * 256 + m] = c;
    c = beta * c + alpha * (part[h * 256 + m] * (1.0f / 2048.0f));
  }
}

// pq = phi(Q * (cs + alpha*(kv - cs))), pk = phi(K); phi(x)=x>0?x+1:exp(x)
// Vectorized: 8 consecutive d-elements per thread (G13 — scalar bf16 loads
// are 2-2.5x slower; this kernel moves ~40 MB).
__global__ __launch_bounds__(256) void pqpk_kernel(
    const u16* __restrict__ Qp, const u16* __restrict__ Kp,
    const u16* __restrict__ kv, const float* __restrict__ cs,
    const float* __restrict__ alphaP, u16* __restrict__ pq,
    u16* __restrict__ pk) {
  long base = ((long)blockIdx.x * 256 + threadIdx.x) * 8;  // (b,h,l,d) packed
  int d0 = (int)(base & 255), l = (int)((base >> 8) & 255),
      h = (int)((base >> 16) & 7), b = (int)(base >> 19);
  float alpha = *alphaP;
  long pidx = ((long)(b * 256 + l)) * 2048 + h * 256 + d0;
  ushort4 q0 = *(const ushort4*)(Qp + pidx);
  ushort4 q1 = *(const ushort4*)(Qp + pidx + 4);
  ushort4 k0 = *(const ushort4*)(Kp + pidx);
  ushort4 k1 = *(const ushort4*)(Kp + pidx + 4);
  ushort4 v0 = *(const ushort4*)(kv + base);
  ushort4 v1 = *(const ushort4*)(kv + base + 4);
  float4 c0 = *(const float4*)(cs + h * 256 + d0);
  float4 c1 = *(const float4*)(cs + h * 256 + d0 + 4);
  u16 qs[8] = {q0.x, q0.y, q0.z, q0.w, q1.x, q1.y, q1.z, q1.w};
  u16 ks[8] = {k0.x, k0.y, k0.z, k0.w, k1.x, k1.y, k1.z, k1.w};
  u16 vs[8] = {v0.x, v0.y, v0.z, v0.w, v1.x, v1.y, v1.z, v1.w};
  float cf[8] = {c0.x, c0.y, c0.z, c0.w, c1.x, c1.y, c1.z, c1.w};
  u16 oq[8], ok[8];
#pragma unroll
  for (int e = 0; e < 8; ++e) {
    float qm = b2f(qs[e]) * (cf[e] + alpha * (b2f(vs[e]) - cf[e]));
    oq[e] = f2b(qm > 0.f ? qm + 1.f : expf(qm));
    float Kv = b2f(ks[e]);
    ok[e] = f2b(Kv > 0.f ? Kv + 1.f : expf(Kv));
  }
  *(ushort4*)(pq + base) = (ushort4){oq[0], oq[1], oq[2], oq[3]};
  *(ushort4*)(pq + base + 4) = (ushort4){oq[4], oq[5], oq[6], oq[7]};
  *(ushort4*)(pk + base) = (ushort4){ok[0], ok[1], ok[2], ok[3]};
  *(ushort4*)(pk + base + 4) = (ushort4){ok[4], ok[5], ok[6], ok[7]};
}

// Vt[b,h,d,j] = V[b*256+j, h*256+d]  (per-(b,h) 256x256 transpose)
__global__ __launch_bounds__(256) void vtrans_kernel(const u16* __restrict__ Vp,
                                                     u16* __restrict__ Vt) {
  __shared__ u16 tile[32][33];
  int z = blockIdx.z, b = z >> 3, h = z & 7;
  int jT = blockIdx.x * 32, dT = blockIdx.y * 32;
  int tx = threadIdx.x, ty = threadIdx.y;  // (32, 8)
#pragma unroll
  for (int ii = 0; ii < 4; ++ii) {
    int j = jT + ty + ii * 8, d = dT + tx;
    tile[ty + ii * 8][tx] = Vp[(long)(b * 256 + j) * 2048 + h * 256 + d];
  }
  __syncthreads();
#pragma unroll
  for (int ii = 0; ii < 4; ++ii) {
    int d = dT + ty + ii * 8, j = jT + tx;
    Vt[(long)z * 65536 + d * 256 + j] = tile[tx][ty + ii * 8];
  }
}

// LayerNorm over rows of 2048; input = x0 + x1 (split-K partials).
__global__ __launch_bounds__(256) void ln_kernel(
    const float* __restrict__ x0, const float* __restrict__ x1,
    const float* __restrict__ g, const float* __restrict__ bb,
    float* __restrict__ out) {
  int row = blockIdx.x, t = threadIdx.x;
  const float4* xr0 = (const float4*)(x0 + (long)row * 2048);
  const float4* xr1 = (const float4*)(x1 + (long)row * 2048);
  float4 a0 = xr0[t], b0 = xr1[t], a1 = xr0[t + 256], b1 = xr1[t + 256];
  float4 v0, v1;
  v0.x = a0.x + b0.x; v0.y = a0.y + b0.y; v0.z = a0.z + b0.z; v0.w = a0.w + b0.w;
  v1.x = a1.x + b1.x; v1.y = a1.y + b1.y; v1.z = a1.z + b1.z; v1.w = a1.w + b1.w;
  float s = v0.x + v0.y + v0.z + v0.w + v1.x + v1.y + v1.z + v1.w;
  float ss = v0.x * v0.x + v0.y * v0.y + v0.z * v0.z + v0.w * v0.w +
             v1.x * v1.x + v1.y * v1.y + v1.z * v1.z + v1.w * v1.w;
  for (int o = 32; o; o >>= 1) { s += __shfl_xor(s, o); ss += __shfl_xor(ss, o); }
  __shared__ float a1s[4], a2s[4];
  int wave = t >> 6, lane = t & 63;
  if (lane == 0) { a1s[wave] = s; a2s[wave] = ss; }
  __syncthreads();
  s = a1s[0] + a1s[1] + a1s[2] + a1s[3];
  ss = a2s[0] + a2s[1] + a2s[2] + a2s[3];
  float mu = s * (1.f / 2048.f);
  float var = ss * (1.f / 2048.f) - mu * mu;
  float rstd = rsqrtf(var + 1e-5f);
  const float4* g4 = (const float4*)g;
  const float4* b4 = (const float4*)bb;
  float4* orow = (float4*)(out + (long)row * 2048);
  float4 gg = g4[t], bv = b4[t], r;
  r.x = (v0.x - mu) * rstd * gg.x + bv.x;
  r.y = (v0.y - mu) * rstd * gg.y + bv.y;
  r.z = (v0.z - mu) * rstd * gg.z + bv.z;
  r.w = (v0.w - mu) * rstd * gg.w + bv.w;
  orow[t] = r;
  gg = g4[t + 256]; bv = b4[t + 256];
  r.x = (v1.x - mu) * rstd * gg.x + bv.x;
  r.y = (v1.y - mu) * rstd * gg.y + bv.y;
  r.z = (v1.z - mu) * rstd * gg.z + bv.z;
  r.w = (v1.w - mu) * rstd * gg.w + bv.w;
  orow[t + 256] = r;
}

extern "C" void kernel_launch(void* const* d_in, const int* in_sizes, int n_in,
                              void* d_out, int out_size, void* d_ws,
                              size_t ws_size, hipStream_t stream) {
  const float* query = (const float*)d_in[0];
  const float* key = (const float*)d_in[1];
  const float* value = (const float*)d_in[2];
  const float* Wq = (const float*)d_in[3];
  const float* Wk = (const float*)d_in[4];
  const float* Wv = (const float*)d_in[5];
  const float* Wo = (const float*)d_in[6];
  const float* bo = (const float*)d_in[7];
  const float* ln_g = (const float*)d_in[8];
  const float* ln_b = (const float*)d_in[9];
  const float* alphaP = (const float*)d_in[10];
  const float* betaP = (const float*)d_in[11];

  char* ws = (char*)d_ws;
  const long SZ = 8388608;  // bytes of one 2048x2048 bf16 tensor
  u16* qb = (u16*)(ws);                // q,k,v bf16 (3*SZ); x1 aliases later
  u16* Wb = (u16*)(ws + 3 * SZ);       // Wq,Wk,Wv,Wo bf16 (4*SZ)
  u16* Qp = (u16*)(ws + 7 * SZ);       // Q,K,V projections bf16 (3*SZ)
  u16* kvb = (u16*)(ws + 10 * SZ);     // kv bf16 (SZ); later aliased by Ab
  u16* pq = (u16*)(ws + 12 * SZ);      // (SZ)
  u16* pk = (u16*)(ws + 13 * SZ);      // (SZ)
  u16* Vt = (u16*)(ws + 14 * SZ);      // (SZ)
  u16* attnb = (u16*)(ws + 15 * SZ);   // (SZ)
  u16* Ab = (u16*)(ws + 10 * SZ);      // aliases kvb (dead after pqpk)
  float* x0 = (float*)(ws + 12 * SZ);  // 16MB, aliases pq/pk (dead after A GEMM)
  float* x1 = (float*)(ws);            // 16MB, aliases qb..vb (dead after proj)
  float* part = (float*)(ws + 16 * SZ);            // 8 KB (atomic-accumulated)
  float* cs = (float*)(ws + 16 * SZ + 16384);      // 8 KB

  u16* Kp = Qp + 4194304;
  u16* Vp = Qp + 8388608;
  u16* Wob = Wb + 3 * 4194304;

  // 0. zero the cs partial-sum accumulator (d_ws is re-poisoned every call)
  hipMemsetAsync(part, 0, 8 * 256 * sizeof(float), stream);

  // 1. fp32 -> bf16 converts (7 tensors)
  convert7<<<28672, 256, 0, stream>>>(query, key, value, Wq, Wk, Wv, Wo, qb);

  // 2. Q/K/V projections: 256^2-tile pipelined GEMM, z=0..2 batched.
  //    Grid 8x8x3 flattened to 192 (XCD-chunk-swizzled in kernel).
  gemm256<0><<<dim3(192, 1, 1), 512, 0, stream>>>(
      qb, 2048, 4194304L, Wb, 2048, 4194304L, (void*)Qp, 2048, 4194304L,
      2048, nullptr, nullptr);

  // 3. kv[b,h,l,m] = sum_d K[b,h,l,d] V[b,h,m,d] (64 batches, bf16 out)
  //    + fused column sums into part[h*256+m] via atomics
  gemm_bt<1, 64><<<dim3(2, 2, 64), 256, 0, stream>>>(
      Kp, 2048, 524288L, 256L, Vp, 2048, 524288L, 256L, (void*)kvb, 256,
      524288L, 65536L, 256, 8, nullptr, nullptr, part);

  // 4. cs scan over heads (head-means already in part)
  cs_kernel<<<1, 256, 0, stream>>>(part, cs, alphaP, betaP);

  // 5. pq = phi(Q*(cs+alpha*(kv-cs))), pk = phi(K)  (8 elems/thread)
  pqpk_kernel<<<2048, 256, 0, stream>>>(Qp, Kp, kvb, cs, alphaP, pq, pk);

  // 6. A = pq @ pk^T, causal-masked, bf16 (overwrites kv region).
  //    Fully-masked block (x=1,y=0) skipped: 3 xy-blocks per batch.
  gemm_bt<2, 64><<<dim3(3, 1, 64), 256, 0, stream>>>(
      pq, 256, 524288L, 65536L, pk, 256, 524288L, 65536L, (void*)Ab, 256,
      524288L, 65536L, 256, 8, nullptr, nullptr, nullptr);

  // 7. V transpose per (b,h): Vt[d,j] = V[j,d]
  vtrans_kernel<<<dim3(8, 8, 64), dim3(32, 8), 0, stream>>>(Vp, Vt);

  // 8. attn = (A @ V) / den, den fused from A-fragments, K clamped causally
  gemm_bt<3, 64><<<dim3(2, 2, 64), 256, 0, stream>>>(
      Ab, 256, 524288L, 65536L, Vt, 256, 524288L, 65536L, (void*)attnb, 2048,
      524288L, 256L, 256, 8, nullptr, nullptr, nullptr);

  // 9. x = attn @ Wo^T (+ bo + query on z=0), split-K=2, 256^2 tiles.
  //    Grid 8x8x2 flattened to 128. sC1 = x1 - x0 = -12*SZ/4 floats.
  gemm256<4><<<dim3(128, 1, 1), 512, 0, stream>>>(
      attnb, 2048, 1024L, Wob, 2048, 1024L, (void*)x0, 2048, -25165824L,
      1024, bo, query);

  // 10. LayerNorm(x0 + x1) -> d_out
  ln_kernel<<<2048, 256, 0, stream>>>(x0, x1, ln_g, ln_b, (float*)d_out);
}

// Round 7
// 340.088 us; speedup vs baseline: 1.6288x; 1.6288x over previous
//
#include <hip/hip_runtime.h>
#include <hip/hip_bf16.h>

using u16 = unsigned short;

typedef __bf16 bf16x8 __attribute__((ext_vector_type(8)));
typedef float  f32x4  __attribute__((ext_vector_type(4)));

typedef __attribute__((address_space(1))) void gas_void;
typedef __attribute__((address_space(3))) void las_void;

__device__ __forceinline__ float b2f(u16 u) {
  union { unsigned u; float f; } v; v.u = ((unsigned)u) << 16; return v.f;
}
__device__ __forceinline__ u16 f2b(float f) {
  union { float f; unsigned u; } v; v.f = f;
  unsigned r = v.u + 0x7fffu + ((v.u >> 16) & 1u);
  return (u16)(r >> 16);
}

// async global->LDS, 16B per lane. LDS dest must be uniform base + lane*16.
__device__ __forceinline__ void gld_lds16(const u16* g, u16* l) {
  __builtin_amdgcn_global_load_lds((gas_void*)g, (las_void*)l, 16, 0, 0);
}

// ---------------------------------------------------------------------------
// Generic NT GEMM: C[m,n] = sum_k A[m,k] * B[n,k], bf16 in, fp32 acc.
// Block tile 128x128, 4 waves (2x2), wave = 4x4 of 16x16x32 MFMA.
// Retained for the small per-(b,h) GEMMs (kv / causal-A / A@V, EPI 1..3).
// ---------------------------------------------------------------------------
template <int EPI, int BK>
__global__ __launch_bounds__(256) void gemm_bt(
    const u16* __restrict__ A, int lda, long sA1, long sA2,
    const u16* __restrict__ B, int ldb, long sB1, long sB2,
    void* __restrict__ Cv, int ldc, long sC1, long sC2,
    int K, int HDIV,
    const float* __restrict__ bias, const float* __restrict__ resid,
    float* __restrict__ partOut) {
  __shared__ __align__(16) u16 lds[2 * 128 * BK];
  __shared__ float denS[128];
  const int t = threadIdx.x;
  const int lane = t & 63;
  const int wave = t >> 6;
  const int wm = wave >> 1, wn = wave & 1;
  const int laneM = lane & 15, quad = lane >> 4;
  const int zb = blockIdx.z / HDIV, zh = blockIdx.z % HDIV;

  int bx = blockIdx.x, by = blockIdx.y;
  if (EPI == 2) { by = (bx >= 1) ? 1 : 0; bx = (bx == 2) ? 1 : 0; }
  const int kEnd = (EPI == 3) ? ((by + 1) * 128 < K ? (by + 1) * 128 : K) : K;

  const u16* Abase = A + zb * sA1 + zh * sA2 + (long)by * 128 * lda;
  const u16* Bbase = B + zb * sB1 + zh * sB2 + (long)bx * 128 * ldb;

  constexpr int STEPS = BK / 16;   // staging steps per operand (2048 elem each)
  constexpr int RPS = 2048 / BK;   // rows per staging step
  constexpr int KK = BK / 32;      // MFMA k-steps per LDS tile
  const int sRow = (BK == 64) ? (t >> 3) : (t >> 2);
  const int sg = (BK == 64) ? (t & 7) : (t & 3);
  const int swz = (BK == 64) ? (sg ^ (sRow & 7)) : (sg ^ ((sRow >> 1) & 3));
  const int sc = swz * 8;  // swizzled global k-chunk offset (elems)

  f32x4 acc[4][4];
#pragma unroll
  for (int i = 0; i < 4; ++i)
#pragma unroll
    for (int j = 0; j < 4; ++j) acc[i][j] = (f32x4){0.f, 0.f, 0.f, 0.f};
  float dsum[4] = {0.f, 0.f, 0.f, 0.f};

  for (int k0 = 0; k0 < kEnd; k0 += BK) {
#pragma unroll
    for (int p = 0; p < STEPS; ++p)
      gld_lds16(Abase + (long)(p * RPS + sRow) * lda + k0 + sc,
                &lds[p * 2048 + t * 8]);
#pragma unroll
    for (int p = 0; p < STEPS; ++p)
      gld_lds16(Bbase + (long)(p * RPS + sRow) * ldb + k0 + sc,
                &lds[128 * BK + p * 2048 + t * 8]);
    __syncthreads();  // drains vmcnt(0): LDS staging complete
    bf16x8 af[KK][4], bfv[KK][4];
#pragma unroll
    for (int kk = 0; kk < KK; ++kk) {
      int perm8;
      if (BK == 64) perm8 = ((kk * 4 + quad) ^ (laneM & 7)) * 8;
      else          perm8 = (quad ^ ((laneM >> 1) & 3)) * 8;
#pragma unroll
      for (int i = 0; i < 4; ++i) {
        af[kk][i] = *(const bf16x8*)&lds[(wm * 64 + i * 16 + laneM) * BK + perm8];
        bfv[kk][i] =
            *(const bf16x8*)&lds[128 * BK + (wn * 64 + i * 16 + laneM) * BK + perm8];
      }
    }
    if (EPI == 3) {  // rowsum of A from fragments (den; mask is pre-applied)
#pragma unroll
      for (int kk = 0; kk < KK; ++kk)
#pragma unroll
        for (int i = 0; i < 4; ++i) {
          union { bf16x8 v; u16 s[8]; } u; u.v = af[kk][i];
          float ds = 0.f;
#pragma unroll
          for (int e = 0; e < 8; ++e) ds += b2f(u.s[e]);
          dsum[i] += ds;
        }
    }
#pragma unroll
    for (int kk = 0; kk < KK; ++kk)
#pragma unroll
      for (int i = 0; i < 4; ++i)
#pragma unroll
        for (int j = 0; j < 4; ++j)
          acc[i][j] = __builtin_amdgcn_mfma_f32_16x16x32_bf16(
              af[kk][i], bfv[kk][j], acc[i][j], 0, 0, 0);
    __syncthreads();  // all waves done reading before next stage
  }

  if (EPI == 3) {
#pragma unroll
    for (int i = 0; i < 4; ++i) {
      float s = dsum[i];
      s += __shfl_xor(s, 16);
      s += __shfl_xor(s, 32);
      if (wn == 0 && quad == 0)
        denS[wm * 64 + i * 16 + laneM] = fmaxf(s, 1e-8f);
    }
    __syncthreads();
  }

  if (EPI == 1) {  // column sums of tile -> part[zh*256 + col] (cs fusion)
#pragma unroll
    for (int j = 0; j < 4; ++j) {
      float s = 0.f;
#pragma unroll
      for (int i = 0; i < 4; ++i)
#pragma unroll
        for (int r = 0; r < 4; ++r) s += acc[i][j][r];
      s += __shfl_xor(s, 16);
      s += __shfl_xor(s, 32);
      if (quad == 0)
        atomicAdd(&partOut[zh * 256 + bx * 128 + wn * 64 + j * 16 + laneM], s);
    }
  }

  const long cOff = zb * sC1 + zh * sC2;
  const int colB = bx * 128 + wn * 64;
#pragma unroll
  for (int i = 0; i < 4; ++i) {
#pragma unroll
    for (int j = 0; j < 4; ++j) {
#pragma unroll
      for (int r = 0; r < 4; ++r) {
        const int lrow = wm * 64 + i * 16 + quad * 4 + r;  // row within block
        const int row = by * 128 + lrow;                   // within-batch row
        const int col = colB + j * 16 + laneM;             // within-batch col
        const long idx = cOff + (long)row * ldc + col;
        float v = acc[i][j][r];
        if (EPI == 0 || EPI == 1) {
          ((u16*)Cv)[idx] = f2b(v);
        } else if (EPI == 2) {
          ((u16*)Cv)[idx] = f2b(col <= row ? v : 0.0f);
        } else if (EPI == 3) {
          ((u16*)Cv)[idx] = f2b(v / denS[lrow]);
        } else {
          ((float*)Cv)[idx] =
              (zb == 0) ? v + bias[col] + resid[(long)row * ldc + col] : v;
        }
      }
    }
  }
}

// ---------------------------------------------------------------------------
// One K-tile (BK=32) of the 256x256 pipelined GEMM (R2-proven structure).
// la/lb: buffers consumed (tile tau); sa/sb: buffers staged (tile tau+3).
// Distinct __shared__ objects + provenance-preserving casts.  Two phases:
// {8+4 ds_read, stage A(tau+3), bar, lgkm(0), 16 MFMA, bar} then
// {4 ds_read, stage B(tau+3), bar, lgkm(0), 16 MFMA}.  Boundary: counted
// vmcnt(8) + barrier; vmcnt(4)/(0) only in the 2-tile tail.
// Measured: 65.8 us proj @ R2 (VGPR 124-128, no spill).  Do NOT add more
// live fragment sets: R6's 3-set cross-half variant spilled (WRITE_SIZE
// 24.6 -> 236 MB, 210 us).
// ---------------------------------------------------------------------------
__device__ __forceinline__ void g256_tile(
    const u16* __restrict__ la, const u16* __restrict__ lb,
    u16* __restrict__ sa, u16* __restrict__ sb, int tau, int nt,
    const u16* AgR0, const u16* AgR1, const u16* BgR0, const u16* BgR1,
    int rowA, int rowB, int rg, int t, f32x4 (&acc)[8][4]) {
  const bool st = (tau + 3) < nt;
  const int ks = (tau + 3) << 5;
  bf16x8 af[4], bv[4];
#pragma unroll
  for (int m = 0; m < 4; ++m)
    af[m] = *(const bf16x8*)&la[(rowA + m * 16) * 32 + rg];
#pragma unroll
  for (int n = 0; n < 4; ++n)
    bv[n] = *(const bf16x8*)&lb[(rowB + n * 16) * 32 + rg];
  if (st) {
    gld_lds16(AgR0 + ks, &sa[t * 8]);
    gld_lds16(AgR1 + ks, &sa[4096 + t * 8]);
  }
  __builtin_amdgcn_s_barrier();
  asm volatile("s_waitcnt lgkmcnt(0)" ::: "memory");
  __builtin_amdgcn_s_setprio(1);
#pragma unroll
  for (int m = 0; m < 4; ++m)
#pragma unroll
    for (int n = 0; n < 4; ++n)
      acc[m][n] = __builtin_amdgcn_mfma_f32_16x16x32_bf16(af[m], bv[n],
                                                          acc[m][n], 0, 0, 0);
  __builtin_amdgcn_s_setprio(0);
  __builtin_amdgcn_s_barrier();
#pragma unroll
  for (int m = 0; m < 4; ++m)
    af[m] = *(const bf16x8*)&la[(rowA + 64 + m * 16) * 32 + rg];
  if (st) {
    gld_lds16(BgR0 + ks, &sb[t * 8]);
    gld_lds16(BgR1 + ks, &sb[4096 + t * 8]);
  }
  __builtin_amdgcn_s_barrier();
  asm volatile("s_waitcnt lgkmcnt(0)" ::: "memory");
  __builtin_amdgcn_s_setprio(1);
#pragma unroll
  for (int m = 0; m < 4; ++m)
#pragma unroll
    for (int n = 0; n < 4; ++n)
      acc[4 + m][n] = __builtin_amdgcn_mfma_f32_16x16x32_bf16(
          af[m], bv[n], acc[4 + m][n], 0, 0, 0);
  __builtin_amdgcn_s_setprio(0);
  if (tau < nt - 1) {
    if (tau + 3 < nt)
      asm volatile("s_waitcnt vmcnt(8)" ::: "memory");
    else if (tau + 2 < nt)
      asm volatile("s_waitcnt vmcnt(4)" ::: "memory");
    else
      asm volatile("s_waitcnt vmcnt(0)" ::: "memory");
    __builtin_amdgcn_s_barrier();
  }
}

// ---------------------------------------------------------------------------
// 256x256 NT GEMM, counted-vmcnt pipeline, STATIC quad-buffered LDS.
// 512 threads = 8 waves (2 M x 4 N); per-wave 128x64 output = 8x4 16x16 frags.
// 4 separate 16KB buffers per operand (128 KB LDS, 1 block/CU), prefetch
// distance 3 tiles, main loop statically unrolled x4 (nt = 64 or 32, %4==0).
// Grid: flat 8*8*Z, bijective chunked XCD swizzle (grid %8==0).
// EPI 0: bf16 out (proj). EPI 4: fp32 out, z==0 adds bias+resid (Wo splitK).
// ---------------------------------------------------------------------------
template <int EPI>
__global__ __launch_bounds__(512) void gemm256(
    const u16* __restrict__ A, int lda, long sA1,
    const u16* __restrict__ B, int ldb, long sB1,
    void* __restrict__ Cv, int ldc, long sC1, int K,
    const float* __restrict__ bias, const float* __restrict__ resid) {
  __shared__ __align__(16) u16 A0[8192], A1[8192], A2[8192], A3[8192];
  __shared__ __align__(16) u16 B0[8192], B1[8192], B2[8192], B3[8192];
  const int t = threadIdx.x;
  const int lane = t & 63, wave = t >> 6;
  const int wm = wave >> 2, wn = wave & 3;
  const int laneM = lane & 15, quad = lane >> 4;

  const int cpx = gridDim.x >> 3;                      // blocks per XCD chunk
  const int id2 = (blockIdx.x & 7) * cpx + (blockIdx.x >> 3);
  const int bx = id2 & 7, by = (id2 >> 3) & 7, z = id2 >> 6;

  const u16* Ag = A + (long)z * sA1 + (long)by * 256 * lda;
  const u16* Bg = B + (long)z * sB1 + (long)bx * 256 * ldb;

  const int nt = K >> 5;                               // K-tiles of 32
  const int rg = (quad ^ ((laneM >> 1) & 3)) * 8;      // read-granule offset
  const int rowA = wm * 128 + laneM;
  const int rowB = wn * 64 + laneM;

  // staging addresses: thread t covers chunks t and 512+t of each tile
  const int sRow0 = t >> 2, sRow1 = (512 + t) >> 2;
  const int sc0 = (((t) & 3) ^ ((sRow0 >> 1) & 3)) * 8;
  const int sc1 = (((512 + t) & 3) ^ ((sRow1 >> 1) & 3)) * 8;
  const u16* AgR0 = Ag + (long)sRow0 * lda + sc0;
  const u16* AgR1 = Ag + (long)sRow1 * lda + sc1;
  const u16* BgR0 = Bg + (long)sRow0 * ldb + sc0;
  const u16* BgR1 = Bg + (long)sRow1 * ldb + sc1;

  f32x4 acc[8][4];
#pragma unroll
  for (int i = 0; i < 8; ++i)
#pragma unroll
    for (int j = 0; j < 4; ++j) acc[i][j] = (f32x4){0.f, 0.f, 0.f, 0.f};

  // prologue: stage tiles 0,1,2 into bufs 0,1,2 (12 loads/thread total);
  // wait only for tile 0 (oldest 4), keep 8 in flight.
  gld_lds16(AgR0, &A0[t * 8]);      gld_lds16(AgR1, &A0[4096 + t * 8]);
  gld_lds16(BgR0, &B0[t * 8]);      gld_lds16(BgR1, &B0[4096 + t * 8]);
  gld_lds16(AgR0 + 32, &A1[t * 8]); gld_lds16(AgR1 + 32, &A1[4096 + t * 8]);
  gld_lds16(BgR0 + 32, &B1[t * 8]); gld_lds16(BgR1 + 32, &B1[4096 + t * 8]);
  gld_lds16(AgR0 + 64, &A2[t * 8]); gld_lds16(AgR1 + 64, &A2[4096 + t * 8]);
  gld_lds16(BgR0 + 64, &B2[t * 8]); gld_lds16(BgR1 + 64, &B2[4096 + t * 8]);
  asm volatile("s_waitcnt vmcnt(8)" ::: "memory");
  __builtin_amdgcn_s_barrier();

  for (int tau = 0; tau < nt; tau += 4) {
    g256_tile(A0, B0, A3, B3, tau, nt, AgR0, AgR1, BgR0, BgR1, rowA, rowB,
              rg, t, acc);
    g256_tile(A1, B1, A0, B0, tau + 1, nt, AgR0, AgR1, BgR0, BgR1, rowA,
              rowB, rg, t, acc);
    g256_tile(A2, B2, A1, B1, tau + 2, nt, AgR0, AgR1, BgR0, BgR1, rowA,
              rowB, rg, t, acc);
    g256_tile(A3, B3, A2, B2, tau + 3, nt, AgR0, AgR1, BgR0, BgR1, rowA,
              rowB, rg, t, acc);
  }

  const long cOff = (long)z * sC1;
  const int colB = bx * 256 + wn * 64;
  const int rowBase = by * 256 + wm * 128;
#pragma unroll
  for (int i = 0; i < 8; ++i) {
#pragma unroll
    for (int j = 0; j < 4; ++j) {
#pragma unroll
      for (int r = 0; r < 4; ++r) {
        const int row = rowBase + i * 16 + quad * 4 + r;
        const int col = colB + j * 16 + laneM;
        const long idx = cOff + (long)row * ldc + col;
        float v = acc[i][j][r];
        if (EPI == 0) {
          ((u16*)Cv)[idx] = f2b(v);
        } else {
          ((float*)Cv)[idx] =
              (z == 0) ? v + bias[col] + resid[(long)row * ldc + col] : v;
        }
      }
    }
  }
}

// ---------------------------------------------------------------------------
// Convert 7 fp32 2048x2048 tensors -> bf16, dsts contiguous from dst base.
// ---------------------------------------------------------------------------
__global__ __launch_bounds__(256) void convert7(
    const float* __restrict__ s0, const float* __restrict__ s1,
    const float* __restrict__ s2, const float* __restrict__ s3,
    const float* __restrict__ s4, const float* __restrict__ s5,
    const float* __restrict__ s6, u16* __restrict__ dst) {
  long idx = (long)blockIdx.x * 256 + threadIdx.x;  // 0 .. 7*1048576-1
  int seg = (int)(idx >> 20);
  long off = (idx & 1048575) << 2;
  const float* s;
  switch (seg) {
    case 0: s = s0; break; case 1: s = s1; break; case 2: s = s2; break;
    case 3: s = s3; break; case 4: s = s4; break; case 5: s = s5; break;
    default: s = s6;
  }
  float4 v = *(const float4*)(s + off);
  ushort4 o;
  o.x = f2b(v.x); o.y = f2b(v.y); o.z = f2b(v.z); o.w = f2b(v.w);
  *(ushort4*)(dst + (long)seg * 4194304 + off) = o;
}

// pq = phi(Q * (cs + alpha*(kv - cs))), pk = phi(K); phi(x)=x>0?x+1:exp(x)
// Vectorized 8 elems/thread (G13) + cs scan FUSED: h is block-uniform
// (each block covers 2048 consecutive (b,h,l,d) elements = 8 l-rows of one
// (b,h)), so each thread recomputes cs[h, d0..d0+7] from part with a <=7
// step recurrence (part is 8 KB, L2-resident).  Removes the serial 1-block
// cs_kernel launch.
__global__ __launch_bounds__(256) void pqpk_kernel(
    const u16* __restrict__ Qp, const u16* __restrict__ Kp,
    const u16* __restrict__ kv, const float* __restrict__ part,
    const float* __restrict__ alphaP, const float* __restrict__ betaP,
    u16* __restrict__ pq, u16* __restrict__ pk) {
  long base = ((long)blockIdx.x * 256 + threadIdx.x) * 8;  // (b,h,l,d) packed
  int d0 = (int)(base & 255), l = (int)((base >> 8) & 255),
      h = (int)((base >> 16) & 7), b = (int)(base >> 19);
  (void)l; (void)b;
  float alpha = *alphaP, beta = *betaP;
  // cs recurrence: c_0 = 0; c_{hh+1} = beta*c_hh + alpha*part[hh]/2048;
  // cs[h] = c_h (pre-update carry).
  float cf[8] = {0.f, 0.f, 0.f, 0.f, 0.f, 0.f, 0.f, 0.f};
  for (int hh = 0; hh < h; ++hh) {  // h uniform within the block
    float4 p0 = *(const float4*)(part + hh * 256 + d0);
    float4 p1 = *(const float4*)(part + hh * 256 + d0 + 4);
    const float sc = alpha * (1.0f / 2048.0f);
    cf[0] = beta * cf[0] + sc * p0.x;
    cf[1] = beta * cf[1] + sc * p0.y;
    cf[2] = beta * cf[2] + sc * p0.z;
    cf[3] = beta * cf[3] + sc * p0.w;
    cf[4] = beta * cf[4] + sc * p1.x;
    cf[5] = beta * cf[5] + sc * p1.y;
    cf[6] = beta * cf[6] + sc * p1.z;
    cf[7] = beta * cf[7] + sc * p1.w;
  }
  long pidx = base;  // (b,h,l,d) packing of Q/K == kv packing? No: Q/K are
  // [b*256+l, 2048] with head-major columns; recompute below.
  pidx = ((long)((int)(base >> 19) * 256 + (int)((base >> 8) & 255))) * 2048 +
         (int)((base >> 16) & 7) * 256 + d0;
  ushort4 q0 = *(const ushort4*)(Qp + pidx);
  ushort4 q1 = *(const ushort4*)(Qp + pidx + 4);
  ushort4 k0 = *(const ushort4*)(Kp + pidx);
  ushort4 k1 = *(const ushort4*)(Kp + pidx + 4);
  ushort4 v0 = *(const ushort4*)(kv + base);
  ushort4 v1 = *(const ushort4*)(kv + base + 4);
  u16 qs[8] = {q0.x, q0.y, q0.z, q0.w, q1.x, q1.y, q1.z, q1.w};
  u16 ks[8] = {k0.x, k0.y, k0.z, k0.w, k1.x, k1.y, k1.z, k1.w};
  u16 vs[8] = {v0.x, v0.y, v0.z, v0.w, v1.x, v1.y, v1.z, v1.w};
  u16 oq[8], ok[8];
#pragma unroll
  for (int e = 0; e < 8; ++e) {
    float qm = b2f(qs[e]) * (cf[e] + alpha * (b2f(vs[e]) - cf[e]));
    oq[e] = f2b(qm > 0.f ? qm + 1.f : expf(qm));
    float Kv = b2f(ks[e]);
    ok[e] = f2b(Kv > 0.f ? Kv + 1.f : expf(Kv));
  }
  *(ushort4*)(pq + base) = (ushort4){oq[0], oq[1], oq[2], oq[3]};
  *(ushort4*)(pq + base + 4) = (ushort4){oq[4], oq[5], oq[6], oq[7]};
  *(ushort4*)(pk + base) = (ushort4){ok[0], ok[1], ok[2], ok[3]};
  *(ushort4*)(pk + base + 4) = (ushort4){ok[4], ok[5], ok[6], ok[7]};
}

// Vt[b,h,d,j] = V[b*256+j, h*256+d]  (per-(b,h) 256x256 transpose)
__global__ __launch_bounds__(256) void vtrans_kernel(const u16* __restrict__ Vp,
                                                     u16* __restrict__ Vt) {
  __shared__ u16 tile[32][33];
  int z = blockIdx.z, b = z >> 3, h = z & 7;
  int jT = blockIdx.x * 32, dT = blockIdx.y * 32;
  int tx = threadIdx.x, ty = threadIdx.y;  // (32, 8)
#pragma unroll
  for (int ii = 0; ii < 4; ++ii) {
    int j = jT + ty + ii * 8, d = dT + tx;
    tile[ty + ii * 8][tx] = Vp[(long)(b * 256 + j) * 2048 + h * 256 + d];
  }
  __syncthreads();
#pragma unroll
  for (int ii = 0; ii < 4; ++ii) {
    int d = dT + ty + ii * 8, j = jT + tx;
    Vt[(long)z * 65536 + d * 256 + j] = tile[tx][ty + ii * 8];
  }
}

// LayerNorm over rows of 2048; input = x0 + x1 (split-K partials).
__global__ __launch_bounds__(256) void ln_kernel(
    const float* __restrict__ x0, const float* __restrict__ x1,
    const float* __restrict__ g, const float* __restrict__ bb,
    float* __restrict__ out) {
  int row = blockIdx.x, t = threadIdx.x;
  const float4* xr0 = (const float4*)(x0 + (long)row * 2048);
  const float4* xr1 = (const float4*)(x1 + (long)row * 2048);
  float4 a0 = xr0[t], b0 = xr1[t], a1 = xr0[t + 256], b1 = xr1[t + 256];
  float4 v0, v1;
  v0.x = a0.x + b0.x; v0.y = a0.y + b0.y; v0.z = a0.z + b0.z; v0.w = a0.w + b0.w;
  v1.x = a1.x + b1.x; v1.y = a1.y + b1.y; v1.z = a1.z + b1.z; v1.w = a1.w + b1.w;
  float s = v0.x + v0.y + v0.z + v0.w + v1.x + v1.y + v1.z + v1.w;
  float ss = v0.x * v0.x + v0.y * v0.y + v0.z * v0.z + v0.w * v0.w +
             v1.x * v1.x + v1.y * v1.y + v1.z * v1.z + v1.w * v1.w;
  for (int o = 32; o; o >>= 1) { s += __shfl_xor(s, o); ss += __shfl_xor(ss, o); }
  __shared__ float a1s[4], a2s[4];
  int wave = t >> 6, lane = t & 63;
  if (lane == 0) { a1s[wave] = s; a2s[wave] = ss; }
  __syncthreads();
  s = a1s[0] + a1s[1] + a1s[2] + a1s[3];
  ss = a2s[0] + a2s[1] + a2s[2] + a2s[3];
  float mu = s * (1.f / 2048.f);
  float var = ss * (1.f / 2048.f) - mu * mu;
  float rstd = rsqrtf(var + 1e-5f);
  const float4* g4 = (const float4*)g;
  const float4* b4 = (const float4*)bb;
  float4* orow = (float4*)(out + (long)row * 2048);
  float4 gg = g4[t], bv = b4[t], r;
  r.x = (v0.x - mu) * rstd * gg.x + bv.x;
  r.y = (v0.y - mu) * rstd * gg.y + bv.y;
  r.z = (v0.z - mu) * rstd * gg.z + bv.z;
  r.w = (v0.w - mu) * rstd * gg.w + bv.w;
  orow[t] = r;
  gg = g4[t + 256]; bv = b4[t + 256];
  r.x = (v1.x - mu) * rstd * gg.x + bv.x;
  r.y = (v1.y - mu) * rstd * gg.y + bv.y;
  r.z = (v1.z - mu) * rstd * gg.z + bv.z;
  r.w = (v1.w - mu) * rstd * gg.w + bv.w;
  orow[t + 256] = r;
}

extern "C" void kernel_launch(void* const* d_in, const int* in_sizes, int n_in,
                              void* d_out, int out_size, void* d_ws,
                              size_t ws_size, hipStream_t stream) {
  const float* query = (const float*)d_in[0];
  const float* key = (const float*)d_in[1];
  const float* value = (const float*)d_in[2];
  const float* Wq = (const float*)d_in[3];
  const float* Wk = (const float*)d_in[4];
  const float* Wv = (const float*)d_in[5];
  const float* Wo = (const float*)d_in[6];
  const float* bo = (const float*)d_in[7];
  const float* ln_g = (const float*)d_in[8];
  const float* ln_b = (const float*)d_in[9];
  const float* alphaP = (const float*)d_in[10];
  const float* betaP = (const float*)d_in[11];

  char* ws = (char*)d_ws;
  const long SZ = 8388608;  // bytes of one 2048x2048 bf16 tensor
  u16* qb = (u16*)(ws);                // q,k,v bf16 (3*SZ); x1 aliases later
  u16* Wb = (u16*)(ws + 3 * SZ);       // Wq,Wk,Wv,Wo bf16 (4*SZ)
  u16* Qp = (u16*)(ws + 7 * SZ);       // Q,K,V projections bf16 (3*SZ)
  u16* kvb = (u16*)(ws + 10 * SZ);     // kv bf16 (SZ); later aliased by Ab
  u16* pq = (u16*)(ws + 12 * SZ);      // (SZ)
  u16* pk = (u16*)(ws + 13 * SZ);      // (SZ)
  u16* Vt = (u16*)(ws + 14 * SZ);      // (SZ)
  u16* attnb = (u16*)(ws + 15 * SZ);   // (SZ)
  u16* Ab = (u16*)(ws + 10 * SZ);      // aliases kvb (dead after pqpk)
  float* x0 = (float*)(ws + 12 * SZ);  // 16MB, aliases pq/pk (dead after A GEMM)
  float* x1 = (float*)(ws);            // 16MB, aliases qb..vb (dead after proj)
  float* part = (float*)(ws + 16 * SZ);            // 8 KB (atomic-accumulated)

  u16* Kp = Qp + 4194304;
  u16* Vp = Qp + 8388608;
  u16* Wob = Wb + 3 * 4194304;

  // 0. zero the cs partial-sum accumulator (d_ws is re-poisoned every call)
  hipMemsetAsync(part, 0, 8 * 256 * sizeof(float), stream);

  // 1. fp32 -> bf16 converts (7 tensors)
  convert7<<<28672, 256, 0, stream>>>(query, key, value, Wq, Wk, Wv, Wo, qb);

  // 2. Q/K/V projections: 256^2-tile pipelined GEMM, z=0..2 batched.
  //    Grid 8x8x3 flattened to 192 (XCD-chunk-swizzled in kernel).
  gemm256<0><<<dim3(192, 1, 1), 512, 0, stream>>>(
      qb, 2048, 4194304L, Wb, 2048, 4194304L, (void*)Qp, 2048, 4194304L,
      2048, nullptr, nullptr);

  // 3. kv[b,h,l,m] = sum_d K[b,h,l,d] V[b,h,m,d] (64 batches, bf16 out)
  //    + fused column sums into part[h*256+m] via atomics
  gemm_bt<1, 64><<<dim3(2, 2, 64), 256, 0, stream>>>(
      Kp, 2048, 524288L, 256L, Vp, 2048, 524288L, 256L, (void*)kvb, 256,
      524288L, 65536L, 256, 8, nullptr, nullptr, part);

  // 4. pq = phi(Q*(cs+alpha*(kv-cs))), pk = phi(K); cs scan fused in-kernel.
  pqpk_kernel<<<2048, 256, 0, stream>>>(Qp, Kp, kvb, part, alphaP, betaP,
                                        pq, pk);

  // 5. A = pq @ pk^T, causal-masked, bf16 (overwrites kv region).
  //    Fully-masked block (x=1,y=0) skipped: 3 xy-blocks per batch.
  gemm_bt<2, 64><<<dim3(3, 1, 64), 256, 0, stream>>>(
      pq, 256, 524288L, 65536L, pk, 256, 524288L, 65536L, (void*)Ab, 256,
      524288L, 65536L, 256, 8, nullptr, nullptr, nullptr);

  // 6. V transpose per (b,h): Vt[d,j] = V[j,d]
  vtrans_kernel<<<dim3(8, 8, 64), dim3(32, 8), 0, stream>>>(Vp, Vt);

  // 7. attn = (A @ V) / den, den fused from A-fragments, K clamped causally
  gemm_bt<3, 64><<<dim3(2, 2, 64), 256, 0, stream>>>(
      Ab, 256, 524288L, 65536L, Vt, 256, 524288L, 65536L, (void*)attnb, 2048,
      524288L, 256L, 256, 8, nullptr, nullptr, nullptr);

  // 8. x = attn @ Wo^T (+ bo + query on z=0), split-K=2, 256^2 tiles.
  //    Grid 8x8x2 flattened to 128. sC1 = x1 - x0 = -12*SZ/4 floats.
  gemm256<4><<<dim3(128, 1, 1), 512, 0, stream>>>(
      attnb, 2048, 1024L, Wob, 2048, 1024L, (void*)x0, 2048, -25165824L,
      1024, bo, query);

  // 9. LayerNorm(x0 + x1) -> d_out
  ln_kernel<<<2048, 256, 0, stream>>>(x0, x1, ln_g, ln_b, (float*)d_out);
}

// Round 8
// 334.054 us; speedup vs baseline: 1.6582x; 1.0181x over previous
//
#include <hip/hip_runtime.h>
#include <hip/hip_bf16.h>

using u16 = unsigned short;

typedef __bf16 bf16x8 __attribute__((ext_vector_type(8)));
typedef float  f32x4  __attribute__((ext_vector_type(4)));

typedef __attribute__((address_space(1))) void gas_void;
typedef __attribute__((address_space(3))) void las_void;

__device__ __forceinline__ float b2f(u16 u) {
  union { unsigned u; float f; } v; v.u = ((unsigned)u) << 16; return v.f;
}
__device__ __forceinline__ u16 f2b(float f) {
  union { float f; unsigned u; } v; v.f = f;
  unsigned r = v.u + 0x7fffu + ((v.u >> 16) & 1u);
  return (u16)(r >> 16);
}

// async global->LDS, 16B per lane. LDS dest must be uniform base + lane*16.
__device__ __forceinline__ void gld_lds16(const u16* g, u16* l) {
  __builtin_amdgcn_global_load_lds((gas_void*)g, (las_void*)l, 16, 0, 0);
}

// ---------------------------------------------------------------------------
// Generic NT GEMM: C[m,n] = sum_k A[m,k] * B[n,k], bf16 in, fp32 acc.
// Block tile 128x128, 4 waves (2x2), wave = 4x4 of 16x16x32 MFMA.
// Still used for the kv GEMM (EPI 1).
// ---------------------------------------------------------------------------
template <int EPI, int BK>
__global__ __launch_bounds__(256) void gemm_bt(
    const u16* __restrict__ A, int lda, long sA1, long sA2,
    const u16* __restrict__ B, int ldb, long sB1, long sB2,
    void* __restrict__ Cv, int ldc, long sC1, long sC2,
    int K, int HDIV,
    const float* __restrict__ bias, const float* __restrict__ resid,
    float* __restrict__ partOut) {
  __shared__ __align__(16) u16 lds[2 * 128 * BK];
  __shared__ float denS[128];
  const int t = threadIdx.x;
  const int lane = t & 63;
  const int wave = t >> 6;
  const int wm = wave >> 1, wn = wave & 1;
  const int laneM = lane & 15, quad = lane >> 4;
  const int zb = blockIdx.z / HDIV, zh = blockIdx.z % HDIV;

  int bx = blockIdx.x, by = blockIdx.y;
  if (EPI == 2) { by = (bx >= 1) ? 1 : 0; bx = (bx == 2) ? 1 : 0; }
  const int kEnd = (EPI == 3) ? ((by + 1) * 128 < K ? (by + 1) * 128 : K) : K;

  const u16* Abase = A + zb * sA1 + zh * sA2 + (long)by * 128 * lda;
  const u16* Bbase = B + zb * sB1 + zh * sB2 + (long)bx * 128 * ldb;

  constexpr int STEPS = BK / 16;   // staging steps per operand (2048 elem each)
  constexpr int RPS = 2048 / BK;   // rows per staging step
  constexpr int KK = BK / 32;      // MFMA k-steps per LDS tile
  const int sRow = (BK == 64) ? (t >> 3) : (t >> 2);
  const int sg = (BK == 64) ? (t & 7) : (t & 3);
  const int swz = (BK == 64) ? (sg ^ (sRow & 7)) : (sg ^ ((sRow >> 1) & 3));
  const int sc = swz * 8;  // swizzled global k-chunk offset (elems)

  f32x4 acc[4][4];
#pragma unroll
  for (int i = 0; i < 4; ++i)
#pragma unroll
    for (int j = 0; j < 4; ++j) acc[i][j] = (f32x4){0.f, 0.f, 0.f, 0.f};
  float dsum[4] = {0.f, 0.f, 0.f, 0.f};

  for (int k0 = 0; k0 < kEnd; k0 += BK) {
#pragma unroll
    for (int p = 0; p < STEPS; ++p)
      gld_lds16(Abase + (long)(p * RPS + sRow) * lda + k0 + sc,
                &lds[p * 2048 + t * 8]);
#pragma unroll
    for (int p = 0; p < STEPS; ++p)
      gld_lds16(Bbase + (long)(p * RPS + sRow) * ldb + k0 + sc,
                &lds[128 * BK + p * 2048 + t * 8]);
    __syncthreads();  // drains vmcnt(0): LDS staging complete
    bf16x8 af[KK][4], bfv[KK][4];
#pragma unroll
    for (int kk = 0; kk < KK; ++kk) {
      int perm8;
      if (BK == 64) perm8 = ((kk * 4 + quad) ^ (laneM & 7)) * 8;
      else          perm8 = (quad ^ ((laneM >> 1) & 3)) * 8;
#pragma unroll
      for (int i = 0; i < 4; ++i) {
        af[kk][i] = *(const bf16x8*)&lds[(wm * 64 + i * 16 + laneM) * BK + perm8];
        bfv[kk][i] =
            *(const bf16x8*)&lds[128 * BK + (wn * 64 + i * 16 + laneM) * BK + perm8];
      }
    }
    if (EPI == 3) {
#pragma unroll
      for (int kk = 0; kk < KK; ++kk)
#pragma unroll
        for (int i = 0; i < 4; ++i) {
          union { bf16x8 v; u16 s[8]; } u; u.v = af[kk][i];
          float ds = 0.f;
#pragma unroll
          for (int e = 0; e < 8; ++e) ds += b2f(u.s[e]);
          dsum[i] += ds;
        }
    }
#pragma unroll
    for (int kk = 0; kk < KK; ++kk)
#pragma unroll
      for (int i = 0; i < 4; ++i)
#pragma unroll
        for (int j = 0; j < 4; ++j)
          acc[i][j] = __builtin_amdgcn_mfma_f32_16x16x32_bf16(
              af[kk][i], bfv[kk][j], acc[i][j], 0, 0, 0);
    __syncthreads();  // all waves done reading before next stage
  }

  if (EPI == 3) {
#pragma unroll
    for (int i = 0; i < 4; ++i) {
      float s = dsum[i];
      s += __shfl_xor(s, 16);
      s += __shfl_xor(s, 32);
      if (wn == 0 && quad == 0)
        denS[wm * 64 + i * 16 + laneM] = fmaxf(s, 1e-8f);
    }
    __syncthreads();
  }

  if (EPI == 1) {  // column sums of tile -> part[zh*256 + col] (cs fusion)
#pragma unroll
    for (int j = 0; j < 4; ++j) {
      float s = 0.f;
#pragma unroll
      for (int i = 0; i < 4; ++i)
#pragma unroll
        for (int r = 0; r < 4; ++r) s += acc[i][j][r];
      s += __shfl_xor(s, 16);
      s += __shfl_xor(s, 32);
      if (quad == 0)
        atomicAdd(&partOut[zh * 256 + bx * 128 + wn * 64 + j * 16 + laneM], s);
    }
  }

  const long cOff = zb * sC1 + zh * sC2;
  const int colB = bx * 128 + wn * 64;
#pragma unroll
  for (int i = 0; i < 4; ++i) {
#pragma unroll
    for (int j = 0; j < 4; ++j) {
#pragma unroll
      for (int r = 0; r < 4; ++r) {
        const int lrow = wm * 64 + i * 16 + quad * 4 + r;  // row within block
        const int row = by * 128 + lrow;                   // within-batch row
        const int col = colB + j * 16 + laneM;             // within-batch col
        const long idx = cOff + (long)row * ldc + col;
        float v = acc[i][j][r];
        if (EPI == 0 || EPI == 1) {
          ((u16*)Cv)[idx] = f2b(v);
        } else if (EPI == 2) {
          ((u16*)Cv)[idx] = f2b(col <= row ? v : 0.0f);
        } else if (EPI == 3) {
          ((u16*)Cv)[idx] = f2b(v / denS[lrow]);
        } else {
          ((float*)Cv)[idx] =
              (zb == 0) ? v + bias[col] + resid[(long)row * ldc + col] : v;
        }
      }
    }
  }
}

// ---------------------------------------------------------------------------
// One K-tile (BK=32) of the 256x256 pipelined GEMM (R2-proven structure).
// Measured: 65.8-68 us proj (VGPR 124, no spill).  Do NOT add more live
// fragment sets: R6's cross-half variant spilled (WRITE 24.6->236 MB).
// ---------------------------------------------------------------------------
__device__ __forceinline__ void g256_tile(
    const u16* __restrict__ la, const u16* __restrict__ lb,
    u16* __restrict__ sa, u16* __restrict__ sb, int tau, int nt,
    const u16* AgR0, const u16* AgR1, const u16* BgR0, const u16* BgR1,
    int rowA, int rowB, int rg, int t, f32x4 (&acc)[8][4]) {
  const bool st = (tau + 3) < nt;
  const int ks = (tau + 3) << 5;
  bf16x8 af[4], bv[4];
#pragma unroll
  for (int m = 0; m < 4; ++m)
    af[m] = *(const bf16x8*)&la[(rowA + m * 16) * 32 + rg];
#pragma unroll
  for (int n = 0; n < 4; ++n)
    bv[n] = *(const bf16x8*)&lb[(rowB + n * 16) * 32 + rg];
  if (st) {
    gld_lds16(AgR0 + ks, &sa[t * 8]);
    gld_lds16(AgR1 + ks, &sa[4096 + t * 8]);
  }
  __builtin_amdgcn_s_barrier();
  asm volatile("s_waitcnt lgkmcnt(0)" ::: "memory");
  __builtin_amdgcn_s_setprio(1);
#pragma unroll
  for (int m = 0; m < 4; ++m)
#pragma unroll
    for (int n = 0; n < 4; ++n)
      acc[m][n] = __builtin_amdgcn_mfma_f32_16x16x32_bf16(af[m], bv[n],
                                                          acc[m][n], 0, 0, 0);
  __builtin_amdgcn_s_setprio(0);
  __builtin_amdgcn_s_barrier();
#pragma unroll
  for (int m = 0; m < 4; ++m)
    af[m] = *(const bf16x8*)&la[(rowA + 64 + m * 16) * 32 + rg];
  if (st) {
    gld_lds16(BgR0 + ks, &sb[t * 8]);
    gld_lds16(BgR1 + ks, &sb[4096 + t * 8]);
  }
  __builtin_amdgcn_s_barrier();
  asm volatile("s_waitcnt lgkmcnt(0)" ::: "memory");
  __builtin_amdgcn_s_setprio(1);
#pragma unroll
  for (int m = 0; m < 4; ++m)
#pragma unroll
    for (int n = 0; n < 4; ++n)
      acc[4 + m][n] = __builtin_amdgcn_mfma_f32_16x16x32_bf16(
          af[m], bv[n], acc[4 + m][n], 0, 0, 0);
  __builtin_amdgcn_s_setprio(0);
  if (tau < nt - 1) {
    if (tau + 3 < nt)
      asm volatile("s_waitcnt vmcnt(8)" ::: "memory");
    else if (tau + 2 < nt)
      asm volatile("s_waitcnt vmcnt(4)" ::: "memory");
    else
      asm volatile("s_waitcnt vmcnt(0)" ::: "memory");
    __builtin_amdgcn_s_barrier();
  }
}

// ---------------------------------------------------------------------------
// 256x256 NT GEMM, counted-vmcnt pipeline, STATIC quad-buffered LDS.
// ---------------------------------------------------------------------------
template <int EPI>
__global__ __launch_bounds__(512) void gemm256(
    const u16* __restrict__ A, int lda, long sA1,
    const u16* __restrict__ B, int ldb, long sB1,
    void* __restrict__ Cv, int ldc, long sC1, int K,
    const float* __restrict__ bias, const float* __restrict__ resid) {
  __shared__ __align__(16) u16 A0[8192], A1[8192], A2[8192], A3[8192];
  __shared__ __align__(16) u16 B0[8192], B1[8192], B2[8192], B3[8192];
  const int t = threadIdx.x;
  const int lane = t & 63, wave = t >> 6;
  const int wm = wave >> 2, wn = wave & 3;
  const int laneM = lane & 15, quad = lane >> 4;

  const int cpx = gridDim.x >> 3;                      // blocks per XCD chunk
  const int id2 = (blockIdx.x & 7) * cpx + (blockIdx.x >> 3);
  const int bx = id2 & 7, by = (id2 >> 3) & 7, z = id2 >> 6;

  const u16* Ag = A + (long)z * sA1 + (long)by * 256 * lda;
  const u16* Bg = B + (long)z * sB1 + (long)bx * 256 * ldb;

  const int nt = K >> 5;                               // K-tiles of 32
  const int rg = (quad ^ ((laneM >> 1) & 3)) * 8;      // read-granule offset
  const int rowA = wm * 128 + laneM;
  const int rowB = wn * 64 + laneM;

  const int sRow0 = t >> 2, sRow1 = (512 + t) >> 2;
  const int sc0 = (((t) & 3) ^ ((sRow0 >> 1) & 3)) * 8;
  const int sc1 = (((512 + t) & 3) ^ ((sRow1 >> 1) & 3)) * 8;
  const u16* AgR0 = Ag + (long)sRow0 * lda + sc0;
  const u16* AgR1 = Ag + (long)sRow1 * lda + sc1;
  const u16* BgR0 = Bg + (long)sRow0 * ldb + sc0;
  const u16* BgR1 = Bg + (long)sRow1 * ldb + sc1;

  f32x4 acc[8][4];
#pragma unroll
  for (int i = 0; i < 8; ++i)
#pragma unroll
    for (int j = 0; j < 4; ++j) acc[i][j] = (f32x4){0.f, 0.f, 0.f, 0.f};

  gld_lds16(AgR0, &A0[t * 8]);      gld_lds16(AgR1, &A0[4096 + t * 8]);
  gld_lds16(BgR0, &B0[t * 8]);      gld_lds16(BgR1, &B0[4096 + t * 8]);
  gld_lds16(AgR0 + 32, &A1[t * 8]); gld_lds16(AgR1 + 32, &A1[4096 + t * 8]);
  gld_lds16(BgR0 + 32, &B1[t * 8]); gld_lds16(BgR1 + 32, &B1[4096 + t * 8]);
  gld_lds16(AgR0 + 64, &A2[t * 8]); gld_lds16(AgR1 + 64, &A2[4096 + t * 8]);
  gld_lds16(BgR0 + 64, &B2[t * 8]); gld_lds16(BgR1 + 64, &B2[4096 + t * 8]);
  asm volatile("s_waitcnt vmcnt(8)" ::: "memory");
  __builtin_amdgcn_s_barrier();

  for (int tau = 0; tau < nt; tau += 4) {
    g256_tile(A0, B0, A3, B3, tau, nt, AgR0, AgR1, BgR0, BgR1, rowA, rowB,
              rg, t, acc);
    g256_tile(A1, B1, A0, B0, tau + 1, nt, AgR0, AgR1, BgR0, BgR1, rowA,
              rowB, rg, t, acc);
    g256_tile(A2, B2, A1, B1, tau + 2, nt, AgR0, AgR1, BgR0, BgR1, rowA,
              rowB, rg, t, acc);
    g256_tile(A3, B3, A2, B2, tau + 3, nt, AgR0, AgR1, BgR0, BgR1, rowA,
              rowB, rg, t, acc);
  }

  const long cOff = (long)z * sC1;
  const int colB = bx * 256 + wn * 64;
  const int rowBase = by * 256 + wm * 128;
#pragma unroll
  for (int i = 0; i < 8; ++i) {
#pragma unroll
    for (int j = 0; j < 4; ++j) {
#pragma unroll
      for (int r = 0; r < 4; ++r) {
        const int row = rowBase + i * 16 + quad * 4 + r;
        const int col = colB + j * 16 + laneM;
        const long idx = cOff + (long)row * ldc + col;
        float v = acc[i][j][r];
        if (EPI == 0) {
          ((u16*)Cv)[idx] = f2b(v);
        } else {
          ((float*)Cv)[idx] =
              (z == 0) ? v + bias[col] + resid[(long)row * ldc + col] : v;
        }
      }
    }
  }
}

// ---------------------------------------------------------------------------
// FUSED causal attention core per (b,h): S = mask(pq @ pk^T) -> bf16 in LDS
// (identical rounding to the old materialized-A path), den = rowsum(S) via
// the EPI3 fragment trick, attn = (S @ V)/den using Vt.  Eliminates the Ab
// HBM round-trip (16 MB) and one dispatch.
// Grid (4,1,64): by = 64-row causal slab (j-tiles 0..by), z = b*8+h.
// 512 thr = 8 waves (2 wm x 4 wn).  Per wave: S 32x16 (2 frags), PV 32x64
// (2x4 frags).  LDS: PQ 32K + PK 32K + VT dbuf 64K + S 9K = 137.5 KB.
// Swizzles: PQ/PK rows 256 elems, granule slot g holds global chunk
// g^(r&7) (gemm_bt BK=64 pattern, 2-way banks); VT rows 64 elems, same XOR;
// S-LDS padded to 72 u16/row (stride 144B -> 2-way banks).
// ---------------------------------------------------------------------------
__global__ __launch_bounds__(512) void fused_av(
    const u16* __restrict__ pq, const u16* __restrict__ pk,
    const u16* __restrict__ Vt, u16* __restrict__ attnb) {
  __shared__ __align__(16) u16 PQ[64 * 256];
  __shared__ __align__(16) u16 PK[64 * 256];
  __shared__ __align__(16) u16 VT0[256 * 64];
  __shared__ __align__(16) u16 VT1[256 * 64];
  __shared__ __align__(16) u16 SL[64 * 72];
  __shared__ float denS[64];
  const int t = threadIdx.x;
  const int lane = t & 63, wave = t >> 6;
  const int wm = wave >> 2, wn = wave & 3;  // 2 x 4
  const int laneM = lane & 15, quad = lane >> 4;
  const int by = blockIdx.x, z = blockIdx.z;
  const int nj = by + 1;  // causal j-tiles
  const long zo = (long)z * 65536;

  const u16* pqg = pq + zo + (long)by * 64 * 256;
  const u16* pkg = pk + zo;
  const u16* vtg = Vt + zo;

  // prologue: stage pq slab + pk tile 0 + Vt tile 0
#pragma unroll
  for (int p = 0; p < 4; ++p) {
    int c = p * 512 + t, r = c >> 5, g = c & 31;
    gld_lds16(pqg + r * 256 + ((g ^ (r & 7)) * 8), &PQ[c * 8]);
  }
#pragma unroll
  for (int p = 0; p < 4; ++p) {
    int c = p * 512 + t, r = c >> 5, g = c & 31;
    gld_lds16(pkg + r * 256 + ((g ^ (r & 7)) * 8), &PK[c * 8]);
  }
#pragma unroll
  for (int p = 0; p < 4; ++p) {
    int c = p * 512 + t, r = c >> 3, g = c & 7;
    gld_lds16(vtg + r * 256 + ((g ^ (r & 7)) * 8), &VT0[c * 8]);
  }
  asm volatile("s_waitcnt vmcnt(0)" ::: "memory");
  __builtin_amdgcn_s_barrier();

  f32x4 acc[2][4];  // PV: rows wm*32+i*16, cols wn*64+jj*16
#pragma unroll
  for (int i = 0; i < 2; ++i)
#pragma unroll
    for (int j = 0; j < 4; ++j) acc[i][j] = (f32x4){0.f, 0.f, 0.f, 0.f};
  float dsum[2] = {0.f, 0.f};

  for (int jt = 0; jt < nj; ++jt) {
    const u16* VT = (jt & 1) ? VT1 : VT0;
    u16* VTn = (jt & 1) ? VT0 : VT1;
    // ---- S = pq @ pk_jt^T: per wave 32(l) x 16(j), K=256 ----
    f32x4 s0 = (f32x4){0.f, 0.f, 0.f, 0.f};
    f32x4 s1 = (f32x4){0.f, 0.f, 0.f, 0.f};
#pragma unroll
    for (int kk = 0; kk < 8; ++kk) {
      const int pg = ((kk * 4 + quad) ^ (laneM & 7)) * 8;
      bf16x8 bk = *(const bf16x8*)&PK[(wn * 16 + laneM) * 256 + pg];
      bf16x8 a0 = *(const bf16x8*)&PQ[(wm * 32 + laneM) * 256 + pg];
      bf16x8 a1 = *(const bf16x8*)&PQ[(wm * 32 + 16 + laneM) * 256 + pg];
      s0 = __builtin_amdgcn_mfma_f32_16x16x32_bf16(a0, bk, s0, 0, 0, 0);
      s1 = __builtin_amdgcn_mfma_f32_16x16x32_bf16(a1, bk, s1, 0, 0, 0);
    }
    // ---- masked bf16 S -> SL (col=laneM j, row=quad*4+r) ----
    {
      const int jcol = jt * 64 + wn * 16 + laneM;  // global j
#pragma unroll
      for (int r = 0; r < 4; ++r) {
        int l0 = wm * 32 + quad * 4 + r;           // slab row, frag i=0
        int l1 = l0 + 16;                          // frag i=1
        SL[l0 * 72 + wn * 16 + laneM] =
            f2b(jcol <= by * 64 + l0 ? s0[r] : 0.f);
        SL[l1 * 72 + wn * 16 + laneM] =
            f2b(jcol <= by * 64 + l1 ? s1[r] : 0.f);
      }
    }
    __builtin_amdgcn_s_barrier();  // S visible; PK consumption complete
    const bool st = (jt + 1) < nj;
    if (st) {  // stage next pk tile + next Vt tile (into the idle buffer)
#pragma unroll
      for (int p = 0; p < 4; ++p) {
        int c = p * 512 + t, r = c >> 5, g = c & 31;
        gld_lds16(pkg + ((jt + 1) * 64 + r) * 256 + ((g ^ (r & 7)) * 8),
                  &PK[c * 8]);
      }
#pragma unroll
      for (int p = 0; p < 4; ++p) {
        int c = p * 512 + t, r = c >> 3, g = c & 7;
        gld_lds16(vtg + r * 256 + (jt + 1) * 64 + ((g ^ (r & 7)) * 8),
                  &VTn[c * 8]);
      }
    }
    // ---- PV: acc += S @ Vt_jt; dsum from S A-fragments (EPI3 trick) ----
#pragma unroll
    for (int kk = 0; kk < 2; ++kk) {
#pragma unroll
      for (int i = 0; i < 2; ++i) {
        bf16x8 sa = *(const bf16x8*)&SL[(wm * 32 + i * 16 + laneM) * 72 +
                                        kk * 32 + quad * 8];
        union { bf16x8 v; u16 s[8]; } u; u.v = sa;
        float ds = 0.f;
#pragma unroll
        for (int e = 0; e < 8; ++e) ds += b2f(u.s[e]);
        dsum[i] += ds;
#pragma unroll
        for (int jj = 0; jj < 4; ++jj) {
          const int drow = wn * 64 + jj * 16 + laneM;
          bf16x8 vb = *(const bf16x8*)&VT[drow * 64 +
                                          (((kk * 4 + quad) ^ (laneM & 7)) * 8)];
          acc[i][jj] =
              __builtin_amdgcn_mfma_f32_16x16x32_bf16(sa, vb, acc[i][jj], 0, 0, 0);
        }
      }
    }
    if (st) asm volatile("s_waitcnt vmcnt(0)" ::: "memory");
    __builtin_amdgcn_s_barrier();  // SL/VT consumption done; stages landed
  }

  // den: lane covers k=quad*8 per kk; shfl over quad halves -> full row sum
#pragma unroll
  for (int i = 0; i < 2; ++i) {
    float s = dsum[i];
    s += __shfl_xor(s, 16);
    s += __shfl_xor(s, 32);
    if (wn == 0 && quad == 0)
      denS[wm * 32 + i * 16 + laneM] = fmaxf(s, 1e-8f);
  }
  __builtin_amdgcn_s_barrier();

  // epilogue: attnb[b*256 + by*64 + l][h*256 + d] = acc/den (bf16)
  const long obase =
      ((long)(z >> 3) * 256 + by * 64) * 2048 + (z & 7) * 256;
#pragma unroll
  for (int i = 0; i < 2; ++i) {
#pragma unroll
    for (int jj = 0; jj < 4; ++jj) {
#pragma unroll
      for (int r = 0; r < 4; ++r) {
        const int lrow = wm * 32 + i * 16 + quad * 4 + r;
        const int d = wn * 64 + jj * 16 + laneM;
        attnb[obase + (long)lrow * 2048 + d] = f2b(acc[i][jj][r] / denS[lrow]);
      }
    }
  }
}

// ---------------------------------------------------------------------------
// Convert 7 fp32 2048x2048 tensors -> bf16, dsts contiguous from dst base.
// ---------------------------------------------------------------------------
__global__ __launch_bounds__(256) void convert7(
    const float* __restrict__ s0, const float* __restrict__ s1,
    const float* __restrict__ s2, const float* __restrict__ s3,
    const float* __restrict__ s4, const float* __restrict__ s5,
    const float* __restrict__ s6, u16* __restrict__ dst) {
  long idx = (long)blockIdx.x * 256 + threadIdx.x;  // 0 .. 7*1048576-1
  int seg = (int)(idx >> 20);
  long off = (idx & 1048575) << 2;
  const float* s;
  switch (seg) {
    case 0: s = s0; break; case 1: s = s1; break; case 2: s = s2; break;
    case 3: s = s3; break; case 4: s = s4; break; case 5: s = s5; break;
    default: s = s6;
  }
  float4 v = *(const float4*)(s + off);
  ushort4 o;
  o.x = f2b(v.x); o.y = f2b(v.y); o.z = f2b(v.z); o.w = f2b(v.w);
  *(ushort4*)(dst + (long)seg * 4194304 + off) = o;
}

// pq = phi(Q * (cs + alpha*(kv - cs))), pk = phi(K); phi(x)=x>0?x+1:exp(x)
// Vectorized 8 elems/thread + cs scan fused (h block-uniform).
__global__ __launch_bounds__(256) void pqpk_kernel(
    const u16* __restrict__ Qp, const u16* __restrict__ Kp,
    const u16* __restrict__ kv, const float* __restrict__ part,
    const float* __restrict__ alphaP, const float* __restrict__ betaP,
    u16* __restrict__ pq, u16* __restrict__ pk) {
  long base = ((long)blockIdx.x * 256 + threadIdx.x) * 8;  // (b,h,l,d) packed
  int d0 = (int)(base & 255), h = (int)((base >> 16) & 7);
  float alpha = *alphaP, beta = *betaP;
  float cf[8] = {0.f, 0.f, 0.f, 0.f, 0.f, 0.f, 0.f, 0.f};
  for (int hh = 0; hh < h; ++hh) {  // h uniform within the block
    float4 p0 = *(const float4*)(part + hh * 256 + d0);
    float4 p1 = *(const float4*)(part + hh * 256 + d0 + 4);
    const float sc = alpha * (1.0f / 2048.0f);
    cf[0] = beta * cf[0] + sc * p0.x;
    cf[1] = beta * cf[1] + sc * p0.y;
    cf[2] = beta * cf[2] + sc * p0.z;
    cf[3] = beta * cf[3] + sc * p0.w;
    cf[4] = beta * cf[4] + sc * p1.x;
    cf[5] = beta * cf[5] + sc * p1.y;
    cf[6] = beta * cf[6] + sc * p1.z;
    cf[7] = beta * cf[7] + sc * p1.w;
  }
  long pidx = ((long)((int)(base >> 19) * 256 + (int)((base >> 8) & 255))) * 2048 +
              h * 256 + d0;
  ushort4 q0 = *(const ushort4*)(Qp + pidx);
  ushort4 q1 = *(const ushort4*)(Qp + pidx + 4);
  ushort4 k0 = *(const ushort4*)(Kp + pidx);
  ushort4 k1 = *(const ushort4*)(Kp + pidx + 4);
  ushort4 v0 = *(const ushort4*)(kv + base);
  ushort4 v1 = *(const ushort4*)(kv + base + 4);
  u16 qs[8] = {q0.x, q0.y, q0.z, q0.w, q1.x, q1.y, q1.z, q1.w};
  u16 ks[8] = {k0.x, k0.y, k0.z, k0.w, k1.x, k1.y, k1.z, k1.w};
  u16 vs[8] = {v0.x, v0.y, v0.z, v0.w, v1.x, v1.y, v1.z, v1.w};
  u16 oq[8], ok[8];
#pragma unroll
  for (int e = 0; e < 8; ++e) {
    float qm = b2f(qs[e]) * (cf[e] + alpha * (b2f(vs[e]) - cf[e]));
    oq[e] = f2b(qm > 0.f ? qm + 1.f : expf(qm));
    float Kv = b2f(ks[e]);
    ok[e] = f2b(Kv > 0.f ? Kv + 1.f : expf(Kv));
  }
  *(ushort4*)(pq + base) = (ushort4){oq[0], oq[1], oq[2], oq[3]};
  *(ushort4*)(pq + base + 4) = (ushort4){oq[4], oq[5], oq[6], oq[7]};
  *(ushort4*)(pk + base) = (ushort4){ok[0], ok[1], ok[2], ok[3]};
  *(ushort4*)(pk + base + 4) = (ushort4){ok[4], ok[5], ok[6], ok[7]};
}

// Vt[b,h,d,j] = V[b*256+j, h*256+d]  (per-(b,h) 256x256 transpose)
__global__ __launch_bounds__(256) void vtrans_kernel(const u16* __restrict__ Vp,
                                                     u16* __restrict__ Vt) {
  __shared__ u16 tile[32][33];
  int z = blockIdx.z, b = z >> 3, h = z & 7;
  int jT = blockIdx.x * 32, dT = blockIdx.y * 32;
  int tx = threadIdx.x, ty = threadIdx.y;  // (32, 8)
#pragma unroll
  for (int ii = 0; ii < 4; ++ii) {
    int j = jT + ty + ii * 8, d = dT + tx;
    tile[ty + ii * 8][tx] = Vp[(long)(b * 256 + j) * 2048 + h * 256 + d];
  }
  __syncthreads();
#pragma unroll
  for (int ii = 0; ii < 4; ++ii) {
    int d = dT + ty + ii * 8, j = jT + tx;
    Vt[(long)z * 65536 + d * 256 + j] = tile[tx][ty + ii * 8];
  }
}

// LayerNorm over rows of 2048; input = x0 + x1 (split-K partials).
__global__ __launch_bounds__(256) void ln_kernel(
    const float* __restrict__ x0, const float* __restrict__ x1,
    const float* __restrict__ g, const float* __restrict__ bb,
    float* __restrict__ out) {
  int row = blockIdx.x, t = threadIdx.x;
  const float4* xr0 = (const float4*)(x0 + (long)row * 2048);
  const float4* xr1 = (const float4*)(x1 + (long)row * 2048);
  float4 a0 = xr0[t], b0 = xr1[t], a1 = xr0[t + 256], b1 = xr1[t + 256];
  float4 v0, v1;
  v0.x = a0.x + b0.x; v0.y = a0.y + b0.y; v0.z = a0.z + b0.z; v0.w = a0.w + b0.w;
  v1.x = a1.x + b1.x; v1.y = a1.y + b1.y; v1.z = a1.z + b1.z; v1.w = a1.w + b1.w;
  float s = v0.x + v0.y + v0.z + v0.w + v1.x + v1.y + v1.z + v1.w;
  float ss = v0.x * v0.x + v0.y * v0.y + v0.z * v0.z + v0.w * v0.w +
             v1.x * v1.x + v1.y * v1.y + v1.z * v1.z + v1.w * v1.w;
  for (int o = 32; o; o >>= 1) { s += __shfl_xor(s, o); ss += __shfl_xor(ss, o); }
  __shared__ float a1s[4], a2s[4];
  int wave = t >> 6, lane = t & 63;
  if (lane == 0) { a1s[wave] = s; a2s[wave] = ss; }
  __syncthreads();
  s = a1s[0] + a1s[1] + a1s[2] + a1s[3];
  ss = a2s[0] + a2s[1] + a2s[2] + a2s[3];
  float mu = s * (1.f / 2048.f);
  float var = ss * (1.f / 2048.f) - mu * mu;
  float rstd = rsqrtf(var + 1e-5f);
  const float4* g4 = (const float4*)g;
  const float4* b4 = (const float4*)bb;
  float4* orow = (float4*)(out + (long)row * 2048);
  float4 gg = g4[t], bv = b4[t], r;
  r.x = (v0.x - mu) * rstd * gg.x + bv.x;
  r.y = (v0.y - mu) * rstd * gg.y + bv.y;
  r.z = (v0.z - mu) * rstd * gg.z + bv.z;
  r.w = (v0.w - mu) * rstd * gg.w + bv.w;
  orow[t] = r;
  gg = g4[t + 256]; bv = b4[t + 256];
  r.x = (v1.x - mu) * rstd * gg.x + bv.x;
  r.y = (v1.y - mu) * rstd * gg.y + bv.y;
  r.z = (v1.z - mu) * rstd * gg.z + bv.z;
  r.w = (v1.w - mu) * rstd * gg.w + bv.w;
  orow[t + 256] = r;
}

extern "C" void kernel_launch(void* const* d_in, const int* in_sizes, int n_in,
                              void* d_out, int out_size, void* d_ws,
                              size_t ws_size, hipStream_t stream) {
  const float* query = (const float*)d_in[0];
  const float* key = (const float*)d_in[1];
  const float* value = (const float*)d_in[2];
  const float* Wq = (const float*)d_in[3];
  const float* Wk = (const float*)d_in[4];
  const float* Wv = (const float*)d_in[5];
  const float* Wo = (const float*)d_in[6];
  const float* bo = (const float*)d_in[7];
  const float* ln_g = (const float*)d_in[8];
  const float* ln_b = (const float*)d_in[9];
  const float* alphaP = (const float*)d_in[10];
  const float* betaP = (const float*)d_in[11];

  char* ws = (char*)d_ws;
  const long SZ = 8388608;  // bytes of one 2048x2048 bf16 tensor
  u16* qb = (u16*)(ws);                // q,k,v bf16 (3*SZ); x1 aliases later
  u16* Wb = (u16*)(ws + 3 * SZ);       // Wq,Wk,Wv,Wo bf16 (4*SZ)
  u16* Qp = (u16*)(ws + 7 * SZ);       // Q,K,V projections bf16 (3*SZ)
  u16* kvb = (u16*)(ws + 10 * SZ);     // kv bf16 (SZ)
  u16* pq = (u16*)(ws + 12 * SZ);      // (SZ)
  u16* pk = (u16*)(ws + 13 * SZ);      // (SZ)
  u16* Vt = (u16*)(ws + 14 * SZ);      // (SZ)
  u16* attnb = (u16*)(ws + 15 * SZ);   // (SZ)
  float* x0 = (float*)(ws + 12 * SZ);  // aliases pq/pk (dead after fused_av)
  float* x1 = (float*)(ws);            // aliases qb..vb (dead after proj)
  float* part = (float*)(ws + 16 * SZ);            // 8 KB (atomic-accumulated)

  u16* Kp = Qp + 4194304;
  u16* Vp = Qp + 8388608;
  u16* Wob = Wb + 3 * 4194304;

  // 0. zero the cs partial-sum accumulator (d_ws is re-poisoned every call)
  hipMemsetAsync(part, 0, 8 * 256 * sizeof(float), stream);

  // 1. fp32 -> bf16 converts (7 tensors)
  convert7<<<28672, 256, 0, stream>>>(query, key, value, Wq, Wk, Wv, Wo, qb);

  // 2. Q/K/V projections: 256^2-tile pipelined GEMM, z=0..2 batched.
  gemm256<0><<<dim3(192, 1, 1), 512, 0, stream>>>(
      qb, 2048, 4194304L, Wb, 2048, 4194304L, (void*)Qp, 2048, 4194304L,
      2048, nullptr, nullptr);

  // 3. kv[b,h,l,m] = sum_d K[b,h,l,d] V[b,h,m,d] (64 batches, bf16 out)
  //    + fused column sums into part[h*256+m] via atomics
  gemm_bt<1, 64><<<dim3(2, 2, 64), 256, 0, stream>>>(
      Kp, 2048, 524288L, 256L, Vp, 2048, 524288L, 256L, (void*)kvb, 256,
      524288L, 65536L, 256, 8, nullptr, nullptr, part);

  // 4. pq = phi(Q*(cs+alpha*(kv-cs))), pk = phi(K); cs scan fused in-kernel.
  pqpk_kernel<<<2048, 256, 0, stream>>>(Qp, Kp, kvb, part, alphaP, betaP,
                                        pq, pk);

  // 5. V transpose per (b,h): Vt[d,j] = V[j,d]
  vtrans_kernel<<<dim3(8, 8, 64), dim3(32, 8), 0, stream>>>(Vp, Vt);

  // 6. FUSED: attn = (mask(pq@pk^T)/den) @ V   (no Ab materialization)
  fused_av<<<dim3(4, 1, 64), 512, 0, stream>>>(pq, pk, Vt, attnb);

  // 7. x = attn @ Wo^T (+ bo + query on z=0), split-K=2, 256^2 tiles.
  gemm256<4><<<dim3(128, 1, 1), 512, 0, stream>>>(
      attnb, 2048, 1024L, Wob, 2048, 1024L, (void*)x0, 2048, -25165824L,
      1024, bo, query);

  // 8. LayerNorm(x0 + x1) -> d_out
  ln_kernel<<<2048, 256, 0, stream>>>(x0, x1, ln_g, ln_b, (float*)d_out);
}

// Round 9
// 313.627 us; speedup vs baseline: 1.7662x; 1.0651x over previous
//
#include <hip/hip_runtime.h>
#include <hip/hip_bf16.h>

using u16 = unsigned short;

typedef __bf16 bf16x8 __attribute__((ext_vector_type(8)));
typedef float  f32x4  __attribute__((ext_vector_type(4)));
typedef u16    u16x8  __attribute__((ext_vector_type(8)));

typedef __attribute__((address_space(1))) void gas_void;
typedef __attribute__((address_space(3))) void las_void;

__device__ __forceinline__ float b2f(u16 u) {
  union { unsigned u; float f; } v; v.u = ((unsigned)u) << 16; return v.f;
}
__device__ __forceinline__ u16 f2b(float f) {
  union { float f; unsigned u; } v; v.f = f;
  unsigned r = v.u + 0x7fffu + ((v.u >> 16) & 1u);
  return (u16)(r >> 16);
}

// async global->LDS, 16B per lane. LDS dest must be uniform base + lane*16.
__device__ __forceinline__ void gld_lds16(const u16* g, u16* l) {
  __builtin_amdgcn_global_load_lds((gas_void*)g, (las_void*)l, 16, 0, 0);
}

// ---------------------------------------------------------------------------
// Generic NT GEMM: C[m,n] = sum_k A[m,k] * B[n,k], bf16 in, fp32 acc.
// Block tile 128x128, 4 waves (2x2), wave = 4x4 of 16x16x32 MFMA.
// Used for kv GEMM (EPI 1) and the Wo split-K GEMM (EPI 4, 512 blocks =
// 2/CU — R0-proven config; the 256^2 Wo ran only 128 blocks = half idle).
// ---------------------------------------------------------------------------
template <int EPI, int BK>
__global__ __launch_bounds__(256) void gemm_bt(
    const u16* __restrict__ A, int lda, long sA1, long sA2,
    const u16* __restrict__ B, int ldb, long sB1, long sB2,
    void* __restrict__ Cv, int ldc, long sC1, long sC2,
    int K, int HDIV,
    const float* __restrict__ bias, const float* __restrict__ resid,
    float* __restrict__ partOut) {
  __shared__ __align__(16) u16 lds[2 * 128 * BK];
  __shared__ float denS[128];
  const int t = threadIdx.x;
  const int lane = t & 63;
  const int wave = t >> 6;
  const int wm = wave >> 1, wn = wave & 1;
  const int laneM = lane & 15, quad = lane >> 4;
  const int zb = blockIdx.z / HDIV, zh = blockIdx.z % HDIV;

  int bx = blockIdx.x, by = blockIdx.y;
  const int kEnd = K;

  const u16* Abase = A + zb * sA1 + zh * sA2 + (long)by * 128 * lda;
  const u16* Bbase = B + zb * sB1 + zh * sB2 + (long)bx * 128 * ldb;

  constexpr int STEPS = BK / 16;   // staging steps per operand (2048 elem each)
  constexpr int RPS = 2048 / BK;   // rows per staging step
  constexpr int KK = BK / 32;      // MFMA k-steps per LDS tile
  const int sRow = (BK == 64) ? (t >> 3) : (t >> 2);
  const int sg = (BK == 64) ? (t & 7) : (t & 3);
  const int swz = (BK == 64) ? (sg ^ (sRow & 7)) : (sg ^ ((sRow >> 1) & 3));
  const int sc = swz * 8;  // swizzled global k-chunk offset (elems)

  f32x4 acc[4][4];
#pragma unroll
  for (int i = 0; i < 4; ++i)
#pragma unroll
    for (int j = 0; j < 4; ++j) acc[i][j] = (f32x4){0.f, 0.f, 0.f, 0.f};

  for (int k0 = 0; k0 < kEnd; k0 += BK) {
#pragma unroll
    for (int p = 0; p < STEPS; ++p)
      gld_lds16(Abase + (long)(p * RPS + sRow) * lda + k0 + sc,
                &lds[p * 2048 + t * 8]);
#pragma unroll
    for (int p = 0; p < STEPS; ++p)
      gld_lds16(Bbase + (long)(p * RPS + sRow) * ldb + k0 + sc,
                &lds[128 * BK + p * 2048 + t * 8]);
    __syncthreads();  // drains vmcnt(0): LDS staging complete
    bf16x8 af[KK][4], bfv[KK][4];
#pragma unroll
    for (int kk = 0; kk < KK; ++kk) {
      int perm8;
      if (BK == 64) perm8 = ((kk * 4 + quad) ^ (laneM & 7)) * 8;
      else          perm8 = (quad ^ ((laneM >> 1) & 3)) * 8;
#pragma unroll
      for (int i = 0; i < 4; ++i) {
        af[kk][i] = *(const bf16x8*)&lds[(wm * 64 + i * 16 + laneM) * BK + perm8];
        bfv[kk][i] =
            *(const bf16x8*)&lds[128 * BK + (wn * 64 + i * 16 + laneM) * BK + perm8];
      }
    }
#pragma unroll
    for (int kk = 0; kk < KK; ++kk)
#pragma unroll
      for (int i = 0; i < 4; ++i)
#pragma unroll
        for (int j = 0; j < 4; ++j)
          acc[i][j] = __builtin_amdgcn_mfma_f32_16x16x32_bf16(
              af[kk][i], bfv[kk][j], acc[i][j], 0, 0, 0);
    __syncthreads();  // all waves done reading before next stage
  }
  (void)denS;

  if (EPI == 1) {  // column sums of tile -> part[zh*256 + col] (cs fusion)
#pragma unroll
    for (int j = 0; j < 4; ++j) {
      float s = 0.f;
#pragma unroll
      for (int i = 0; i < 4; ++i)
#pragma unroll
        for (int r = 0; r < 4; ++r) s += acc[i][j][r];
      s += __shfl_xor(s, 16);
      s += __shfl_xor(s, 32);
      if (quad == 0)
        atomicAdd(&partOut[zh * 256 + bx * 128 + wn * 64 + j * 16 + laneM], s);
    }
  }

  const long cOff = zb * sC1 + zh * sC2;
  const int colB = bx * 128 + wn * 64;
#pragma unroll
  for (int i = 0; i < 4; ++i) {
#pragma unroll
    for (int j = 0; j < 4; ++j) {
#pragma unroll
      for (int r = 0; r < 4; ++r) {
        const int lrow = wm * 64 + i * 16 + quad * 4 + r;  // row within block
        const int row = by * 128 + lrow;                   // within-batch row
        const int col = colB + j * 16 + laneM;             // within-batch col
        const long idx = cOff + (long)row * ldc + col;
        float v = acc[i][j][r];
        if (EPI == 0 || EPI == 1) {
          ((u16*)Cv)[idx] = f2b(v);
        } else {
          ((float*)Cv)[idx] =
              (zb == 0) ? v + bias[col] + resid[(long)row * ldc + col] : v;
        }
      }
    }
  }
}

// ---------------------------------------------------------------------------
// One K-tile (BK=32) of the 256x256 pipelined GEMM (R2-proven structure).
// Measured: 65.8-70 us proj (VGPR 124, no spill).  Do NOT add more live
// fragment sets: R6's cross-half variant spilled (WRITE 24.6->236 MB).
// ---------------------------------------------------------------------------
__device__ __forceinline__ void g256_tile(
    const u16* __restrict__ la, const u16* __restrict__ lb,
    u16* __restrict__ sa, u16* __restrict__ sb, int tau, int nt,
    const u16* AgR0, const u16* AgR1, const u16* BgR0, const u16* BgR1,
    int rowA, int rowB, int rg, int t, f32x4 (&acc)[8][4]) {
  const bool st = (tau + 3) < nt;
  const int ks = (tau + 3) << 5;
  bf16x8 af[4], bv[4];
#pragma unroll
  for (int m = 0; m < 4; ++m)
    af[m] = *(const bf16x8*)&la[(rowA + m * 16) * 32 + rg];
#pragma unroll
  for (int n = 0; n < 4; ++n)
    bv[n] = *(const bf16x8*)&lb[(rowB + n * 16) * 32 + rg];
  if (st) {
    gld_lds16(AgR0 + ks, &sa[t * 8]);
    gld_lds16(AgR1 + ks, &sa[4096 + t * 8]);
  }
  __builtin_amdgcn_s_barrier();
  asm volatile("s_waitcnt lgkmcnt(0)" ::: "memory");
  __builtin_amdgcn_s_setprio(1);
#pragma unroll
  for (int m = 0; m < 4; ++m)
#pragma unroll
    for (int n = 0; n < 4; ++n)
      acc[m][n] = __builtin_amdgcn_mfma_f32_16x16x32_bf16(af[m], bv[n],
                                                          acc[m][n], 0, 0, 0);
  __builtin_amdgcn_s_setprio(0);
  __builtin_amdgcn_s_barrier();
#pragma unroll
  for (int m = 0; m < 4; ++m)
    af[m] = *(const bf16x8*)&la[(rowA + 64 + m * 16) * 32 + rg];
  if (st) {
    gld_lds16(BgR0 + ks, &sb[t * 8]);
    gld_lds16(BgR1 + ks, &sb[4096 + t * 8]);
  }
  __builtin_amdgcn_s_barrier();
  asm volatile("s_waitcnt lgkmcnt(0)" ::: "memory");
  __builtin_amdgcn_s_setprio(1);
#pragma unroll
  for (int m = 0; m < 4; ++m)
#pragma unroll
    for (int n = 0; n < 4; ++n)
      acc[4 + m][n] = __builtin_amdgcn_mfma_f32_16x16x32_bf16(
          af[m], bv[n], acc[4 + m][n], 0, 0, 0);
  __builtin_amdgcn_s_setprio(0);
  if (tau < nt - 1) {
    if (tau + 3 < nt)
      asm volatile("s_waitcnt vmcnt(8)" ::: "memory");
    else if (tau + 2 < nt)
      asm volatile("s_waitcnt vmcnt(4)" ::: "memory");
    else
      asm volatile("s_waitcnt vmcnt(0)" ::: "memory");
    __builtin_amdgcn_s_barrier();
  }
}

// ---------------------------------------------------------------------------
// 256x256 NT GEMM, counted-vmcnt pipeline, STATIC quad-buffered LDS.
// Used for the Q/K/V projection only (192 blocks, K=2048).
// ---------------------------------------------------------------------------
template <int EPI>
__global__ __launch_bounds__(512) void gemm256(
    const u16* __restrict__ A, int lda, long sA1,
    const u16* __restrict__ B, int ldb, long sB1,
    void* __restrict__ Cv, int ldc, long sC1, int K,
    const float* __restrict__ bias, const float* __restrict__ resid) {
  __shared__ __align__(16) u16 A0[8192], A1[8192], A2[8192], A3[8192];
  __shared__ __align__(16) u16 B0[8192], B1[8192], B2[8192], B3[8192];
  const int t = threadIdx.x;
  const int lane = t & 63, wave = t >> 6;
  const int wm = wave >> 2, wn = wave & 3;
  const int laneM = lane & 15, quad = lane >> 4;

  const int cpx = gridDim.x >> 3;                      // blocks per XCD chunk
  const int id2 = (blockIdx.x & 7) * cpx + (blockIdx.x >> 3);
  const int bx = id2 & 7, by = (id2 >> 3) & 7, z = id2 >> 6;

  const u16* Ag = A + (long)z * sA1 + (long)by * 256 * lda;
  const u16* Bg = B + (long)z * sB1 + (long)bx * 256 * ldb;

  const int nt = K >> 5;                               // K-tiles of 32
  const int rg = (quad ^ ((laneM >> 1) & 3)) * 8;      // read-granule offset
  const int rowA = wm * 128 + laneM;
  const int rowB = wn * 64 + laneM;

  const int sRow0 = t >> 2, sRow1 = (512 + t) >> 2;
  const int sc0 = (((t) & 3) ^ ((sRow0 >> 1) & 3)) * 8;
  const int sc1 = (((512 + t) & 3) ^ ((sRow1 >> 1) & 3)) * 8;
  const u16* AgR0 = Ag + (long)sRow0 * lda + sc0;
  const u16* AgR1 = Ag + (long)sRow1 * lda + sc1;
  const u16* BgR0 = Bg + (long)sRow0 * ldb + sc0;
  const u16* BgR1 = Bg + (long)sRow1 * ldb + sc1;

  f32x4 acc[8][4];
#pragma unroll
  for (int i = 0; i < 8; ++i)
#pragma unroll
    for (int j = 0; j < 4; ++j) acc[i][j] = (f32x4){0.f, 0.f, 0.f, 0.f};

  gld_lds16(AgR0, &A0[t * 8]);      gld_lds16(AgR1, &A0[4096 + t * 8]);
  gld_lds16(BgR0, &B0[t * 8]);      gld_lds16(BgR1, &B0[4096 + t * 8]);
  gld_lds16(AgR0 + 32, &A1[t * 8]); gld_lds16(AgR1 + 32, &A1[4096 + t * 8]);
  gld_lds16(BgR0 + 32, &B1[t * 8]); gld_lds16(BgR1 + 32, &B1[4096 + t * 8]);
  gld_lds16(AgR0 + 64, &A2[t * 8]); gld_lds16(AgR1 + 64, &A2[4096 + t * 8]);
  gld_lds16(BgR0 + 64, &B2[t * 8]); gld_lds16(BgR1 + 64, &B2[4096 + t * 8]);
  asm volatile("s_waitcnt vmcnt(8)" ::: "memory");
  __builtin_amdgcn_s_barrier();

  for (int tau = 0; tau < nt; tau += 4) {
    g256_tile(A0, B0, A3, B3, tau, nt, AgR0, AgR1, BgR0, BgR1, rowA, rowB,
              rg, t, acc);
    g256_tile(A1, B1, A0, B0, tau + 1, nt, AgR0, AgR1, BgR0, BgR1, rowA,
              rowB, rg, t, acc);
    g256_tile(A2, B2, A1, B1, tau + 2, nt, AgR0, AgR1, BgR0, BgR1, rowA,
              rowB, rg, t, acc);
    g256_tile(A3, B3, A2, B2, tau + 3, nt, AgR0, AgR1, BgR0, BgR1, rowA,
              rowB, rg, t, acc);
  }

  const long cOff = (long)z * sC1;
  const int colB = bx * 256 + wn * 64;
  const int rowBase = by * 256 + wm * 128;
#pragma unroll
  for (int i = 0; i < 8; ++i) {
#pragma unroll
    for (int j = 0; j < 4; ++j) {
#pragma unroll
      for (int r = 0; r < 4; ++r) {
        const int row = rowBase + i * 16 + quad * 4 + r;
        const int col = colB + j * 16 + laneM;
        const long idx = cOff + (long)row * ldc + col;
        float v = acc[i][j][r];
        if (EPI == 0) {
          ((u16*)Cv)[idx] = f2b(v);
        } else {
          ((float*)Cv)[idx] =
              (z == 0) ? v + bias[col] + resid[(long)row * ldc + col] : v;
        }
      }
    }
  }
}

// ---------------------------------------------------------------------------
// FUSED causal attention core per (b,h): S = mask(pq @ pk^T) -> bf16 in LDS,
// den = rowsum(S) via fragments, attn = (S @ V)/den using Vt.
// (R8-verified; absmax unchanged vs materialized-A path.)
// ---------------------------------------------------------------------------
__global__ __launch_bounds__(512) void fused_av(
    const u16* __restrict__ pq, const u16* __restrict__ pk,
    const u16* __restrict__ Vt, u16* __restrict__ attnb) {
  __shared__ __align__(16) u16 PQ[64 * 256];
  __shared__ __align__(16) u16 PK[64 * 256];
  __shared__ __align__(16) u16 VT0[256 * 64];
  __shared__ __align__(16) u16 VT1[256 * 64];
  __shared__ __align__(16) u16 SL[64 * 72];
  __shared__ float denS[64];
  const int t = threadIdx.x;
  const int lane = t & 63, wave = t >> 6;
  const int wm = wave >> 2, wn = wave & 3;  // 2 x 4
  const int laneM = lane & 15, quad = lane >> 4;
  const int by = blockIdx.x, z = blockIdx.z;
  const int nj = by + 1;  // causal j-tiles
  const long zo = (long)z * 65536;

  const u16* pqg = pq + zo + (long)by * 64 * 256;
  const u16* pkg = pk + zo;
  const u16* vtg = Vt + zo;

#pragma unroll
  for (int p = 0; p < 4; ++p) {
    int c = p * 512 + t, r = c >> 5, g = c & 31;
    gld_lds16(pqg + r * 256 + ((g ^ (r & 7)) * 8), &PQ[c * 8]);
  }
#pragma unroll
  for (int p = 0; p < 4; ++p) {
    int c = p * 512 + t, r = c >> 5, g = c & 31;
    gld_lds16(pkg + r * 256 + ((g ^ (r & 7)) * 8), &PK[c * 8]);
  }
#pragma unroll
  for (int p = 0; p < 4; ++p) {
    int c = p * 512 + t, r = c >> 3, g = c & 7;
    gld_lds16(vtg + r * 256 + ((g ^ (r & 7)) * 8), &VT0[c * 8]);
  }
  asm volatile("s_waitcnt vmcnt(0)" ::: "memory");
  __builtin_amdgcn_s_barrier();

  f32x4 acc[2][4];
#pragma unroll
  for (int i = 0; i < 2; ++i)
#pragma unroll
    for (int j = 0; j < 4; ++j) acc[i][j] = (f32x4){0.f, 0.f, 0.f, 0.f};
  float dsum[2] = {0.f, 0.f};

  for (int jt = 0; jt < nj; ++jt) {
    const u16* VT = (jt & 1) ? VT1 : VT0;
    u16* VTn = (jt & 1) ? VT0 : VT1;
    f32x4 s0 = (f32x4){0.f, 0.f, 0.f, 0.f};
    f32x4 s1 = (f32x4){0.f, 0.f, 0.f, 0.f};
#pragma unroll
    for (int kk = 0; kk < 8; ++kk) {
      const int pg = ((kk * 4 + quad) ^ (laneM & 7)) * 8;
      bf16x8 bk = *(const bf16x8*)&PK[(wn * 16 + laneM) * 256 + pg];
      bf16x8 a0 = *(const bf16x8*)&PQ[(wm * 32 + laneM) * 256 + pg];
      bf16x8 a1 = *(const bf16x8*)&PQ[(wm * 32 + 16 + laneM) * 256 + pg];
      s0 = __builtin_amdgcn_mfma_f32_16x16x32_bf16(a0, bk, s0, 0, 0, 0);
      s1 = __builtin_amdgcn_mfma_f32_16x16x32_bf16(a1, bk, s1, 0, 0, 0);
    }
    {
      const int jcol = jt * 64 + wn * 16 + laneM;  // global j
#pragma unroll
      for (int r = 0; r < 4; ++r) {
        int l0 = wm * 32 + quad * 4 + r;
        int l1 = l0 + 16;
        SL[l0 * 72 + wn * 16 + laneM] =
            f2b(jcol <= by * 64 + l0 ? s0[r] : 0.f);
        SL[l1 * 72 + wn * 16 + laneM] =
            f2b(jcol <= by * 64 + l1 ? s1[r] : 0.f);
      }
    }
    __builtin_amdgcn_s_barrier();
    const bool st = (jt + 1) < nj;
    if (st) {
#pragma unroll
      for (int p = 0; p < 4; ++p) {
        int c = p * 512 + t, r = c >> 5, g = c & 31;
        gld_lds16(pkg + ((jt + 1) * 64 + r) * 256 + ((g ^ (r & 7)) * 8),
                  &PK[c * 8]);
      }
#pragma unroll
      for (int p = 0; p < 4; ++p) {
        int c = p * 512 + t, r = c >> 3, g = c & 7;
        gld_lds16(vtg + r * 256 + (jt + 1) * 64 + ((g ^ (r & 7)) * 8),
                  &VTn[c * 8]);
      }
    }
#pragma unroll
    for (int kk = 0; kk < 2; ++kk) {
#pragma unroll
      for (int i = 0; i < 2; ++i) {
        bf16x8 sa = *(const bf16x8*)&SL[(wm * 32 + i * 16 + laneM) * 72 +
                                        kk * 32 + quad * 8];
        union { bf16x8 v; u16 s[8]; } u; u.v = sa;
        float ds = 0.f;
#pragma unroll
        for (int e = 0; e < 8; ++e) ds += b2f(u.s[e]);
        dsum[i] += ds;
#pragma unroll
        for (int jj = 0; jj < 4; ++jj) {
          const int drow = wn * 64 + jj * 16 + laneM;
          bf16x8 vb = *(const bf16x8*)&VT[drow * 64 +
                                          (((kk * 4 + quad) ^ (laneM & 7)) * 8)];
          acc[i][jj] =
              __builtin_amdgcn_mfma_f32_16x16x32_bf16(sa, vb, acc[i][jj], 0, 0, 0);
        }
      }
    }
    if (st) asm volatile("s_waitcnt vmcnt(0)" ::: "memory");
    __builtin_amdgcn_s_barrier();
  }

#pragma unroll
  for (int i = 0; i < 2; ++i) {
    float s = dsum[i];
    s += __shfl_xor(s, 16);
    s += __shfl_xor(s, 32);
    if (wn == 0 && quad == 0)
      denS[wm * 32 + i * 16 + laneM] = fmaxf(s, 1e-8f);
  }
  __builtin_amdgcn_s_barrier();

  const long obase =
      ((long)(z >> 3) * 256 + by * 64) * 2048 + (z & 7) * 256;
#pragma unroll
  for (int i = 0; i < 2; ++i) {
#pragma unroll
    for (int jj = 0; jj < 4; ++jj) {
#pragma unroll
      for (int r = 0; r < 4; ++r) {
        const int lrow = wm * 32 + i * 16 + quad * 4 + r;
        const int d = wn * 64 + jj * 16 + laneM;
        attnb[obase + (long)lrow * 2048 + d] = f2b(acc[i][jj][r] / denS[lrow]);
      }
    }
  }
}

// ---------------------------------------------------------------------------
// Convert 7 fp32 2048x2048 tensors -> bf16 + zero the part accumulator
// (blocks >= 28672) — folds the hipMemsetAsync dispatch into this launch.
// ---------------------------------------------------------------------------
__global__ __launch_bounds__(256) void convert7(
    const float* __restrict__ s0, const float* __restrict__ s1,
    const float* __restrict__ s2, const float* __restrict__ s3,
    const float* __restrict__ s4, const float* __restrict__ s5,
    const float* __restrict__ s6, u16* __restrict__ dst,
    float* __restrict__ part) {
  if (blockIdx.x >= 28672) {
    int m = (blockIdx.x - 28672) * 256 + threadIdx.x;
    if (m < 2048) part[m] = 0.f;
    return;
  }
  long idx = (long)blockIdx.x * 256 + threadIdx.x;  // 0 .. 7*1048576-1
  int seg = (int)(idx >> 20);
  long off = (idx & 1048575) << 2;
  const float* s;
  switch (seg) {
    case 0: s = s0; break; case 1: s = s1; break; case 2: s = s2; break;
    case 3: s = s3; break; case 4: s = s4; break; case 5: s = s5; break;
    default: s = s6;
  }
  float4 v = *(const float4*)(s + off);
  ushort4 o;
  o.x = f2b(v.x); o.y = f2b(v.y); o.z = f2b(v.z); o.w = f2b(v.w);
  *(ushort4*)(dst + (long)seg * 4194304 + off) = o;
}

// ---------------------------------------------------------------------------
// MERGED launch: blocks [0,2048) = pqpk (vectorized, cs scan fused);
// blocks [2048,3072) = V transpose (vectorized via 64x72 LDS tile).
// Both depend only on {proj outputs, kv+part}, so one launch after kv.
// pqpk: pq = phi(Q*(cs+alpha*(kv-cs))), pk = phi(K); phi(x)=x>0?x+1:exp(x).
// vtrans: Vt[z][d][j] = Vp[b*256+j][h*256+d]; u16x8 global loads AND stores
// (old kernel was scalar u16 — G13 violation); scalar only on the LDS
// transpose read (<=4-way conflicts, pad 72).
// ---------------------------------------------------------------------------
__global__ __launch_bounds__(256) void pqpk_vt_kernel(
    const u16* __restrict__ Qp, const u16* __restrict__ Kp,
    const u16* __restrict__ kv, const float* __restrict__ part,
    const float* __restrict__ alphaP, const float* __restrict__ betaP,
    u16* __restrict__ pq, u16* __restrict__ pk,
    const u16* __restrict__ Vp, u16* __restrict__ Vt) {
  __shared__ __align__(16) u16 tile[64][72];
  const int t = threadIdx.x;
  const int bid = blockIdx.x;
  if (bid >= 2048) {  // ---- vtrans part ----
    const int vt = bid - 2048;
    const int z = vt >> 4, rem = vt & 15;
    const int jT = (rem & 3) * 64, dT = (rem >> 2) * 64;
    const int b = z >> 3, h = z & 7;
    const int jr = t >> 2, ds = (t & 3) * 16;
    const u16* src = Vp + (long)(b * 256 + jT + jr) * 2048 + h * 256 + dT + ds;
    *(u16x8*)&tile[jr][ds] = *(const u16x8*)src;
    *(u16x8*)&tile[jr][ds + 8] = *(const u16x8*)(src + 8);
    __syncthreads();
    const int dr = t >> 2, js = (t & 3) * 16;
    union { u16x8 v; u16 s[8]; } o0, o1;
#pragma unroll
    for (int k = 0; k < 8; ++k) {
      o0.s[k] = tile[js + k][dr];
      o1.s[k] = tile[js + 8 + k][dr];
    }
    u16* dstp = Vt + (long)z * 65536 + (long)(dT + dr) * 256 + jT + js;
    *(u16x8*)dstp = o0.v;
    *(u16x8*)(dstp + 8) = o1.v;
    return;
  }
  // ---- pqpk part (R7/R8-verified) ----
  long base = ((long)bid * 256 + t) * 8;  // (b,h,l,d) packed
  int d0 = (int)(base & 255), h = (int)((base >> 16) & 7);
  float alpha = *alphaP, beta = *betaP;
  float cf[8] = {0.f, 0.f, 0.f, 0.f, 0.f, 0.f, 0.f, 0.f};
  for (int hh = 0; hh < h; ++hh) {  // h uniform within the block
    float4 p0 = *(const float4*)(part + hh * 256 + d0);
    float4 p1 = *(const float4*)(part + hh * 256 + d0 + 4);
    const float sc = alpha * (1.0f / 2048.0f);
    cf[0] = beta * cf[0] + sc * p0.x;
    cf[1] = beta * cf[1] + sc * p0.y;
    cf[2] = beta * cf[2] + sc * p0.z;
    cf[3] = beta * cf[3] + sc * p0.w;
    cf[4] = beta * cf[4] + sc * p1.x;
    cf[5] = beta * cf[5] + sc * p1.y;
    cf[6] = beta * cf[6] + sc * p1.z;
    cf[7] = beta * cf[7] + sc * p1.w;
  }
  long pidx = ((long)((int)(base >> 19) * 256 + (int)((base >> 8) & 255))) * 2048 +
              h * 256 + d0;
  ushort4 q0 = *(const ushort4*)(Qp + pidx);
  ushort4 q1 = *(const ushort4*)(Qp + pidx + 4);
  ushort4 k0 = *(const ushort4*)(Kp + pidx);
  ushort4 k1 = *(const ushort4*)(Kp + pidx + 4);
  ushort4 v0 = *(const ushort4*)(kv + base);
  ushort4 v1 = *(const ushort4*)(kv + base + 4);
  u16 qs[8] = {q0.x, q0.y, q0.z, q0.w, q1.x, q1.y, q1.z, q1.w};
  u16 ks[8] = {k0.x, k0.y, k0.z, k0.w, k1.x, k1.y, k1.z, k1.w};
  u16 vs[8] = {v0.x, v0.y, v0.z, v0.w, v1.x, v1.y, v1.z, v1.w};
  u16 oq[8], ok[8];
#pragma unroll
  for (int e = 0; e < 8; ++e) {
    float qm = b2f(qs[e]) * (cf[e] + alpha * (b2f(vs[e]) - cf[e]));
    oq[e] = f2b(qm > 0.f ? qm + 1.f : expf(qm));
    float Kv = b2f(ks[e]);
    ok[e] = f2b(Kv > 0.f ? Kv + 1.f : expf(Kv));
  }
  *(ushort4*)(pq + base) = (ushort4){oq[0], oq[1], oq[2], oq[3]};
  *(ushort4*)(pq + base + 4) = (ushort4){oq[4], oq[5], oq[6], oq[7]};
  *(ushort4*)(pk + base) = (ushort4){ok[0], ok[1], ok[2], ok[3]};
  *(ushort4*)(pk + base + 4) = (ushort4){ok[4], ok[5], ok[6], ok[7]};
}

// LayerNorm over rows of 2048; input = x0 + x1 (split-K partials).
__global__ __launch_bounds__(256) void ln_kernel(
    const float* __restrict__ x0, const float* __restrict__ x1,
    const float* __restrict__ g, const float* __restrict__ bb,
    float* __restrict__ out) {
  int row = blockIdx.x, t = threadIdx.x;
  const float4* xr0 = (const float4*)(x0 + (long)row * 2048);
  const float4* xr1 = (const float4*)(x1 + (long)row * 2048);
  float4 a0 = xr0[t], b0 = xr1[t], a1 = xr0[t + 256], b1 = xr1[t + 256];
  float4 v0, v1;
  v0.x = a0.x + b0.x; v0.y = a0.y + b0.y; v0.z = a0.z + b0.z; v0.w = a0.w + b0.w;
  v1.x = a1.x + b1.x; v1.y = a1.y + b1.y; v1.z = a1.z + b1.z; v1.w = a1.w + b1.w;
  float s = v0.x + v0.y + v0.z + v0.w + v1.x + v1.y + v1.z + v1.w;
  float ss = v0.x * v0.x + v0.y * v0.y + v0.z * v0.z + v0.w * v0.w +
             v1.x * v1.x + v1.y * v1.y + v1.z * v1.z + v1.w * v1.w;
  for (int o = 32; o; o >>= 1) { s += __shfl_xor(s, o); ss += __shfl_xor(ss, o); }
  __shared__ float a1s[4], a2s[4];
  int wave = t >> 6, lane = t & 63;
  if (lane == 0) { a1s[wave] = s; a2s[wave] = ss; }
  __syncthreads();
  s = a1s[0] + a1s[1] + a1s[2] + a1s[3];
  ss = a2s[0] + a2s[1] + a2s[2] + a2s[3];
  float mu = s * (1.f / 2048.f);
  float var = ss * (1.f / 2048.f) - mu * mu;
  float rstd = rsqrtf(var + 1e-5f);
  const float4* g4 = (const float4*)g;
  const float4* b4 = (const float4*)bb;
  float4* orow = (float4*)(out + (long)row * 2048);
  float4 gg = g4[t], bv = b4[t], r;
  r.x = (v0.x - mu) * rstd * gg.x + bv.x;
  r.y = (v0.y - mu) * rstd * gg.y + bv.y;
  r.z = (v0.z - mu) * rstd * gg.z + bv.z;
  r.w = (v0.w - mu) * rstd * gg.w + bv.w;
  orow[t] = r;
  gg = g4[t + 256]; bv = b4[t + 256];
  r.x = (v1.x - mu) * rstd * gg.x + bv.x;
  r.y = (v1.y - mu) * rstd * gg.y + bv.y;
  r.z = (v1.z - mu) * rstd * gg.z + bv.z;
  r.w = (v1.w - mu) * rstd * gg.w + bv.w;
  orow[t + 256] = r;
}

extern "C" void kernel_launch(void* const* d_in, const int* in_sizes, int n_in,
                              void* d_out, int out_size, void* d_ws,
                              size_t ws_size, hipStream_t stream) {
  const float* query = (const float*)d_in[0];
  const float* key = (const float*)d_in[1];
  const float* value = (const float*)d_in[2];
  const float* Wq = (const float*)d_in[3];
  const float* Wk = (const float*)d_in[4];
  const float* Wv = (const float*)d_in[5];
  const float* Wo = (const float*)d_in[6];
  const float* bo = (const float*)d_in[7];
  const float* ln_g = (const float*)d_in[8];
  const float* ln_b = (const float*)d_in[9];
  const float* alphaP = (const float*)d_in[10];
  const float* betaP = (const float*)d_in[11];

  char* ws = (char*)d_ws;
  const long SZ = 8388608;  // bytes of one 2048x2048 bf16 tensor
  u16* qb = (u16*)(ws);                // q,k,v bf16 (3*SZ); x1 aliases later
  u16* Wb = (u16*)(ws + 3 * SZ);       // Wq,Wk,Wv,Wo bf16 (4*SZ)
  u16* Qp = (u16*)(ws + 7 * SZ);       // Q,K,V projections bf16 (3*SZ)
  u16* kvb = (u16*)(ws + 10 * SZ);     // kv bf16 (SZ)
  u16* pq = (u16*)(ws + 12 * SZ);      // (SZ)
  u16* pk = (u16*)(ws + 13 * SZ);      // (SZ)
  u16* Vt = (u16*)(ws + 14 * SZ);      // (SZ)
  u16* attnb = (u16*)(ws + 15 * SZ);   // (SZ)
  float* x0 = (float*)(ws + 12 * SZ);  // aliases pq/pk (dead after fused_av)
  float* x1 = (float*)(ws);            // aliases qb..vb (dead after proj)
  float* part = (float*)(ws + 16 * SZ);            // 8 KB (atomic-accumulated)

  u16* Kp = Qp + 4194304;
  u16* Vp = Qp + 8388608;
  u16* Wob = Wb + 3 * 4194304;

  // 1. fp32 -> bf16 converts (7 tensors) + zero part (fused, 8 extra blocks)
  convert7<<<28680, 256, 0, stream>>>(query, key, value, Wq, Wk, Wv, Wo, qb,
                                      part);

  // 2. Q/K/V projections: 256^2-tile pipelined GEMM, z=0..2 batched.
  gemm256<0><<<dim3(192, 1, 1), 512, 0, stream>>>(
      qb, 2048, 4194304L, Wb, 2048, 4194304L, (void*)Qp, 2048, 4194304L,
      2048, nullptr, nullptr);

  // 3. kv[b,h,l,m] = sum_d K[b,h,l,d] V[b,h,m,d] (64 batches, bf16 out)
  //    + fused column sums into part[h*256+m] via atomics
  gemm_bt<1, 64><<<dim3(2, 2, 64), 256, 0, stream>>>(
      Kp, 2048, 524288L, 256L, Vp, 2048, 524288L, 256L, (void*)kvb, 256,
      524288L, 65536L, 256, 8, nullptr, nullptr, part);

  // 4. MERGED: pqpk (blocks 0..2047) + vectorized V transpose (2048..3071)
  pqpk_vt_kernel<<<3072, 256, 0, stream>>>(Qp, Kp, kvb, part, alphaP, betaP,
                                           pq, pk, Vp, Vt);

  // 5. FUSED: attn = (mask(pq@pk^T)/den) @ V   (no Ab materialization)
  fused_av<<<dim3(4, 1, 64), 512, 0, stream>>>(pq, pk, Vt, attnb);

  // 6. x = attn @ Wo^T (+ bo + query on z=0), split-K=2, 128^2 tiles
  //    (512 blocks = 2/CU; the 256^2 version ran only 128 blocks).
  gemm_bt<4, 32><<<dim3(16, 16, 2), 256, 0, stream>>>(
      attnb, 2048, 1024L, 0L, Wob, 2048, 1024L, 0L, (void*)x0, 2048,
      -25165824L, 0L, 1024, 1, bo, query, nullptr);

  // 7. LayerNorm(x0 + x1) -> d_out
  ln_kernel<<<2048, 256, 0, stream>>>(x0, x1, ln_g, ln_b, (float*)d_out);
}